// Round 4
// baseline (1318.409 us; speedup 1.0000x reference)
//
#include <hip/hip_runtime.h>

typedef unsigned short u16;
typedef __bf16 bf16x8 __attribute__((ext_vector_type(8)));
typedef float f32x4 __attribute__((ext_vector_type(4)));

#define AS1 __attribute__((address_space(1)))
#define AS3 __attribute__((address_space(3)))
#define MFMA(a,b,c) __builtin_amdgcn_mfma_f32_16x16x32_bf16(a,b,c,0,0,0)

__device__ __forceinline__ u16 f2bf(float f) {
    union { float f; unsigned u; } x; x.f = f;
    unsigned r = x.u + 0x7fffu + ((x.u >> 16) & 1u);
    return (u16)(r >> 16);
}

// ---------------- img fp32 -> bf16, same [B,C,H,W] layout ----------------
__global__ void k_img_bf16(const float* __restrict__ in, u16* __restrict__ o)
{
    size_t i = ((size_t)blockIdx.x*256 + threadIdx.x)*8;
    float4 a = *(const float4*)(in + i);
    float4 b = *(const float4*)(in + i + 4);
    union { u16 u[8]; uint4 v; } pk;
    pk.u[0]=f2bf(a.x); pk.u[1]=f2bf(a.y); pk.u[2]=f2bf(a.z); pk.u[3]=f2bf(a.w);
    pk.u[4]=f2bf(b.x); pk.u[5]=f2bf(b.y); pk.u[6]=f2bf(b.z); pk.u[7]=f2bf(b.w);
    *(uint4*)(o + i) = pk.v;
}

// ---------------- patch_w prep: pwT[n][k'] = w[k(k')][n] bf16, k' = c*256 + p1*16 + p2 ----------------
__global__ void k_prep_pw(const float* __restrict__ in, u16* __restrict__ o)
{
    __shared__ float T[32*33];
    int kp0 = blockIdx.x*32, n0 = blockIdx.y*32;
    int t = threadIdx.x, r = t >> 5, cc = t & 31;
    #pragma unroll
    for (int i = 0; i < 4; ++i) {
        int kp = kp0 + r + i*8;
        int korig = ((kp >> 4) & 15)*2048 + (kp & 15)*128 + (kp >> 8);
        T[(r + i*8)*33 + cc] = in[(size_t)korig*512 + n0 + cc];
    }
    __syncthreads();
    #pragma unroll
    for (int i = 0; i < 4; ++i)
        o[(size_t)(n0 + r + i*8)*32768 + kp0 + cc] = f2bf(T[cc*33 + r + i*8]);
}

// ---------------- all small weight transposes in ONE launch: out[N][K] = f2bf(in[K][N]^T) ----------------
struct PrepArgs {
    const float* src[12];
    u16* dst[12];
    int K[12];
    int N[12];
};
__global__ void k_prep_weights(PrepArgs a)
{
    __shared__ float T[32*33];
    int z = blockIdx.z;
    int K = a.K[z], N = a.N[z];
    int kt = blockIdx.x*32, nt = blockIdx.y*32;
    if (kt >= K || nt >= N) return;
    const float* in = a.src[z];
    u16* o = a.dst[z];
    int t = threadIdx.x, r = t >> 5, c = t & 31;
    #pragma unroll
    for (int i = 0; i < 4; ++i)
        T[(r + i*8)*33 + c] = in[(size_t)(kt + r + i*8)*N + nt + c];
    __syncthreads();
    #pragma unroll
    for (int i = 0; i < 4; ++i)
        o[(size_t)(nt + r + i*8)*K + kt + c] = f2bf(T[c*33 + r + i*8]);
}

// ---------------- implicit patch-embed GEMM: part[z] = patches(imgb) @ pwT^T (K-slice z) ----------------
// A: bf16 img, staged via global_load_lds with PER-LANE global source (m173 pattern)
// into fragment-major Af (linear LDS dest). B: proven row-major gload_lds path.
// Epilogue: plain stores to per-z slab (no atomics); k_reduce_x sums slabs.
__global__ __launch_bounds__(256) void k_gemm_patch(
    const u16* __restrict__ imgb, const u16* __restrict__ Bt,
    float* __restrict__ part)
{
    __shared__ alignas(16) u16 Af[16*512];   // 16 frags x (64 lanes x 8 bf16)
    __shared__ alignas(16) u16 Bs[128*64];
    const int t = threadIdx.x;
    const int bid = blockIdx.x;
    const int xcd = bid & 7, rr = bid >> 3;
    const int nt = rr & 3, q = rr >> 2;
    const int mz = q*8 + xcd;                 // [0,256) bijective
    const int mt = mz & 31, z = mz >> 5;
    const int m0 = mt*128, n0 = nt*128;
    const int b = m0 >> 10, gh0 = (m0 & 1023) >> 5;
    const int kz = z*4096;
    const int wave = t >> 6, lane = t & 63;
    const int r16 = lane & 15, g = lane >> 4;
    const int wmh = wave >> 1;
    const int wm = wmh*64, wn = (wave & 1)*64;

    const u16* Bb = Bt + (size_t)(n0 + (t>>3))*32768 + kz + (t&7)*8;
    u16* Bsd = Bs + t*8;

    const u16* imgB = imgb + (size_t)b*33554432 + (size_t)gh0*8192;
    int foff[4];
    #pragma unroll
    for (int i = 0; i < 4; ++i) {
        int F = i*4 + wave;
        int im_ = (F >> 1) & 3, ks = F & 1, wh = F >> 3;
        int mb = wh*64 + im_*16 + r16;
        int p1l = ks*2 + (g >> 1), p2b = (g & 1)*8;
        foff[i] = ((mb >> 5)*16 + p1l)*512 + (mb & 31)*16 + p2b;
    }

    f32x4 acc[4][4];
    const f32x4 z4 = {0.f,0.f,0.f,0.f};
    #pragma unroll
    for (int im_ = 0; im_ < 4; ++im_)
        #pragma unroll
        for (int in_ = 0; in_ < 4; ++in_) acc[im_][in_] = z4;

    for (int k = 0; k < 4096; k += 64) {
        const int koff = kz + k;
        const u16* srcK = imgB + (size_t)(koff >> 8)*262144 + ((koff >> 4) & 15)*512;
        #pragma unroll
        for (int i = 0; i < 4; ++i)
            __builtin_amdgcn_global_load_lds((AS1 void*)(Bb + (size_t)i*32*32768 + k), (AS3 void*)(Bsd + i*2048), 16, 0, 0);
        #pragma unroll
        for (int i = 0; i < 4; ++i) {
            const int F = i*4 + wave;
            __builtin_amdgcn_global_load_lds((AS1 void*)(srcK + foff[i]), (AS3 void*)(Af + F*512 + lane*8), 16, 0, 0);
        }
        __syncthreads();
        #pragma unroll
        for (int kk = 0; kk < 64; kk += 32) {
            const int ks = kk >> 5;
            bf16x8 af[4], bfr[4];
            #pragma unroll
            for (int im_ = 0; im_ < 4; ++im_)
                af[im_] = *(const bf16x8*)(Af + (wmh*8 + im_*2 + ks)*512 + lane*8);
            #pragma unroll
            for (int in_ = 0; in_ < 4; ++in_)
                bfr[in_] = *(const bf16x8*)(Bs + (wn + in_*16 + r16)*64 + kk + g*8);
            #pragma unroll
            for (int im_ = 0; im_ < 4; ++im_)
                #pragma unroll
                for (int in_ = 0; in_ < 4; ++in_)
                    acc[im_][in_] = MFMA(af[im_], bfr[in_], acc[im_][in_]);
        }
        __syncthreads();
    }
    float* slab = part + (size_t)z*2097152;
    #pragma unroll
    for (int im_ = 0; im_ < 4; ++im_) {
        int row = m0 + wm + im_*16 + g*4;
        #pragma unroll
        for (int in_ = 0; in_ < 4; ++in_) {
            int col = n0 + wn + in_*16 + r16;
            #pragma unroll
            for (int r4 = 0; r4 < 4; ++r4)
                slab[(size_t)(row + r4)*512 + col] = acc[im_][in_][r4];
        }
    }
}

// ---------------- reduce: x = patch_b + pos_emb + sum_z part[z] ----------------
__global__ void k_reduce_x(const float* __restrict__ part, const float* __restrict__ pb,
                           const float* __restrict__ pe, float* __restrict__ x)
{
    size_t base = ((size_t)blockIdx.x*256 + threadIdx.x)*4;
    float4 s = *(const float4*)(pb + (base & 511));
    float4 e = *(const float4*)(pe + (base & 524287));
    s.x += e.x; s.y += e.y; s.z += e.z; s.w += e.w;
    #pragma unroll
    for (int z = 0; z < 8; ++z) {
        float4 p = *(const float4*)(part + (size_t)z*2097152 + base);
        s.x += p.x; s.y += p.y; s.z += p.z; s.w += p.w;
    }
    *(float4*)(x + base) = s;
}

// ---------------- LayerNorm: 4 rows per 256-thread block (1 wave/row), fp32 in -> bf16 out ----------------
__global__ __launch_bounds__(256) void k_ln(const float* __restrict__ x, const float* __restrict__ sc,
                                            const float* __restrict__ bi, u16* __restrict__ o)
{
    int row = blockIdx.x*4 + (threadIdx.x >> 6), lane = threadIdx.x & 63;
    const float* xr = x + (size_t)row*512 + lane*8;
    float4 v0 = *(const float4*)xr;
    float4 v1 = *(const float4*)(xr + 4);
    float vv[8] = {v0.x,v0.y,v0.z,v0.w,v1.x,v1.y,v1.z,v1.w};
    float sum = 0.f, sq = 0.f;
    #pragma unroll
    for (int i = 0; i < 8; ++i) { sum += vv[i]; sq += vv[i]*vv[i]; }
    #pragma unroll
    for (int m = 1; m < 64; m <<= 1) { sum += __shfl_xor(sum, m, 64); sq += __shfl_xor(sq, m, 64); }
    float mean = sum * (1.f/512.f);
    float var  = sq  * (1.f/512.f) - mean*mean;
    float rstd = rsqrtf(var + 1e-5f);
    int d = lane*8;
    union { u16 u[8]; uint4 v; } pk;
    #pragma unroll
    for (int i = 0; i < 8; ++i) pk.u[i] = f2bf((vv[i]-mean)*rstd*sc[d+i] + bi[d+i]);
    *(uint4*)(o + (size_t)row*512 + d) = pk.v;
}

// ---------------- small-N bf16 GEMM: 64x64x64 tiles, 4 waves, 2x2 frags/wave ----------------
// EPI: 1 = bf16 store, 2 = gelu(acc+bias) bf16, 3 = Cf += acc+bias
template<int EPI>
__global__ __launch_bounds__(256) void k_gemm64(
    const u16* __restrict__ A, int lda,
    const u16* __restrict__ Bt, int ldb,
    int Kblk,
    float* __restrict__ Cf, u16* __restrict__ Cb, int ldc,
    const float* __restrict__ bias)
{
    __shared__ alignas(16) u16 As[64*64];
    __shared__ alignas(16) u16 Bs[64*64];
    const int t = threadIdx.x;
    const int m0 = blockIdx.x*64, n0 = blockIdx.y*64;
    const int wave = t >> 6, lane = t & 63;
    const int wm = (wave >> 1)*32, wn = (wave & 1)*32;
    const int r16 = lane & 15, g = lane >> 4;
    const u16* Ab = A + (size_t)(m0 + (t>>3))*lda + (t&7)*8;
    const u16* Bb = Bt + (size_t)(n0 + (t>>3))*ldb + (t&7)*8;
    u16* Asd = As + t*8;
    u16* Bsd = Bs + t*8;
    f32x4 acc[2][2];
    const f32x4 z4 = {0.f,0.f,0.f,0.f};
    #pragma unroll
    for (int im = 0; im < 2; ++im)
        #pragma unroll
        for (int in_ = 0; in_ < 2; ++in_) acc[im][in_] = z4;

    for (int k = 0; k < Kblk; k += 64) {
        #pragma unroll
        for (int i = 0; i < 2; ++i) {
            __builtin_amdgcn_global_load_lds((AS1 void*)(Ab + (size_t)i*32*lda + k), (AS3 void*)(Asd + i*2048), 16, 0, 0);
            __builtin_amdgcn_global_load_lds((AS1 void*)(Bb + (size_t)i*32*ldb + k), (AS3 void*)(Bsd + i*2048), 16, 0, 0);
        }
        __syncthreads();
        #pragma unroll
        for (int kk = 0; kk < 64; kk += 32) {
            bf16x8 af[2], bfr[2];
            #pragma unroll
            for (int im = 0; im < 2; ++im)
                af[im] = *(const bf16x8*)(As + (wm + im*16 + r16)*64 + kk + g*8);
            #pragma unroll
            for (int in_ = 0; in_ < 2; ++in_)
                bfr[in_] = *(const bf16x8*)(Bs + (wn + in_*16 + r16)*64 + kk + g*8);
            #pragma unroll
            for (int im = 0; im < 2; ++im)
                #pragma unroll
                for (int in_ = 0; in_ < 2; ++in_)
                    acc[im][in_] = MFMA(af[im], bfr[in_], acc[im][in_]);
        }
        __syncthreads();
    }
    #pragma unroll
    for (int im = 0; im < 2; ++im) {
        int row = m0 + wm + im*16 + g*4;
        #pragma unroll
        for (int in_ = 0; in_ < 2; ++in_) {
            int col = n0 + wn + in_*16 + r16;
            #pragma unroll
            for (int r = 0; r < 4; ++r) {
                float v = acc[im][in_][r];
                size_t idx = (size_t)(row + r)*ldc + col;
                if constexpr (EPI == 1) {
                    Cb[idx] = f2bf(v);
                } else if constexpr (EPI == 2) {
                    float xv = v + bias[col];
                    Cb[idx] = f2bf(0.5f*xv*(1.f + erff(xv*0.70710678118654752f)));
                } else {
                    Cf[idx] += v + bias[col];
                }
            }
        }
    }
}

// ---------------- flash attention with relative position bias ----------------
// K/V double-buffered in LDS, ONE barrier per kt-tile (stage kt+1 at loop top).
__global__ __launch_bounds__(256) void k_attn(
    const u16* __restrict__ qkv, const float* __restrict__ bt,
    u16* __restrict__ o, int H)
{
    const int LD = 80;
    __shared__ alignas(16) u16 Qs[64*80];
    __shared__ alignas(16) u16 Ks[2][64*80], Vs[2][64*80];
    __shared__ alignas(16) u16 Ps[4][16*80];
    const int inner = H*64, s3 = 3*inner;
    const int qt = blockIdx.x, head = blockIdx.y, b = blockIdx.z;
    const int t = threadIdx.x, wave = t >> 6, lane = t & 63;
    const int r16 = lane & 15, g = lane >> 4;
    const int q0 = qt*64;
    const size_t tokbase = (size_t)b*1024;
    const int hoff = head*64;

    #pragma unroll
    for (int it = 0; it < 2; ++it) {
        int flat = it*256 + t, r = flat >> 3, d0 = (flat & 7)*8;
        uint4 v = *(const uint4*)(qkv + (tokbase + q0 + r)*s3 + hoff + d0);
        *(uint4*)(Qs + r*LD + d0) = v;
    }

    auto stageKV = [&](int kt, int bufi) {
        const int key0 = kt*64;
        #pragma unroll
        for (int it = 0; it < 2; ++it) {
            int flat = it*256 + t, r = flat >> 3, d0 = (flat & 7)*8;
            uint4 v = *(const uint4*)(qkv + (tokbase + key0 + r)*s3 + inner + hoff + d0);
            *(uint4*)(Ks[bufi] + r*LD + d0) = v;
        }
        #pragma unroll
        for (int it = 0; it < 2; ++it) {
            int flat = it*256 + t, key = flat & 63, d0 = (flat >> 6)*8;
            uint4 v = *(const uint4*)(qkv + (tokbase + key0 + key)*s3 + 2*inner + hoff + d0);
            const u16* pv = (const u16*)&v;
            #pragma unroll
            for (int i = 0; i < 8; ++i) Vs[bufi][(d0+i)*LD + key] = pv[i];
        }
    };

    stageKV(0, 0);
    __syncthreads();

    bf16x8 aQ0 = *(const bf16x8*)(Qs + (wave*16 + r16)*LD + g*8);
    bf16x8 aQ1 = *(const bf16x8*)(Qs + (wave*16 + r16)*LD + 32 + g*8);

    float m_[4], l_[4];
    f32x4 O[4];
    const f32x4 z4 = {0.f,0.f,0.f,0.f};
    #pragma unroll
    for (int r = 0; r < 4; ++r) { m_[r] = -1e30f; l_[r] = 0.f; O[r] = z4; }
    const int qg_base = q0 + wave*16 + g*4;

    for (int kt = 0; kt < 16; ++kt) {
        const int cur = kt & 1;
        if (kt < 15) stageKV(kt + 1, cur ^ 1);
        const int key0 = kt*64;
        const u16* Kc = Ks[cur];
        const u16* Vc = Vs[cur];

        float Sv[4][4];
        #pragma unroll
        for (int kb = 0; kb < 4; ++kb) {
            bf16x8 k0f = *(const bf16x8*)(Kc + (kb*16 + r16)*LD + g*8);
            bf16x8 k1f = *(const bf16x8*)(Kc + (kb*16 + r16)*LD + 32 + g*8);
            f32x4 S = z4;
            S = MFMA(aQ0, k0f, S);
            S = MFMA(aQ1, k1f, S);
            int keyg = key0 + kb*16 + r16;
            int kgh = keyg >> 5, kgw = keyg & 31;
            #pragma unroll
            for (int r = 0; r < 4; ++r) {
                int qg = qg_base + r;
                int rel = ((qg >> 5) - kgh + 31)*63 + ((qg & 31) - kgw + 31);
                Sv[kb][r] = S[r]*0.125f + bt[rel*H + head];
            }
        }
        float mx[4], al[4], ps[4];
        #pragma unroll
        for (int r = 0; r < 4; ++r)
            mx[r] = fmaxf(fmaxf(Sv[0][r], Sv[1][r]), fmaxf(Sv[2][r], Sv[3][r]));
        #pragma unroll
        for (int msk = 1; msk < 16; msk <<= 1)
            #pragma unroll
            for (int r = 0; r < 4; ++r) mx[r] = fmaxf(mx[r], __shfl_xor(mx[r], msk, 64));
        #pragma unroll
        for (int r = 0; r < 4; ++r) {
            float nm = fmaxf(m_[r], mx[r]);
            al[r] = __expf(m_[r] - nm);
            m_[r] = nm;
            ps[r] = 0.f;
        }
        #pragma unroll
        for (int kb = 0; kb < 4; ++kb)
            #pragma unroll
            for (int r = 0; r < 4; ++r) {
                float p = __expf(Sv[kb][r] - m_[r]);
                Sv[kb][r] = p;
                ps[r] += p;
            }
        #pragma unroll
        for (int msk = 1; msk < 16; msk <<= 1)
            #pragma unroll
            for (int r = 0; r < 4; ++r) ps[r] += __shfl_xor(ps[r], msk, 64);
        #pragma unroll
        for (int r = 0; r < 4; ++r) l_[r] = l_[r]*al[r] + ps[r];
        #pragma unroll
        for (int kb = 0; kb < 4; ++kb)
            #pragma unroll
            for (int r = 0; r < 4; ++r)
                Ps[wave][(g*4 + r)*LD + kb*16 + r16] = f2bf(Sv[kb][r]);
        #pragma unroll
        for (int dt = 0; dt < 4; ++dt)
            #pragma unroll
            for (int r = 0; r < 4; ++r) O[dt][r] = O[dt][r]*al[r];
        // Ps[wave] write->read is same-wave: compiler's lgkmcnt wait suffices, no barrier.
        bf16x8 aP0 = *(const bf16x8*)(Ps[wave] + r16*LD + g*8);
        bf16x8 aP1 = *(const bf16x8*)(Ps[wave] + r16*LD + 32 + g*8);
        #pragma unroll
        for (int dt = 0; dt < 4; ++dt) {
            bf16x8 v0 = *(const bf16x8*)(Vc + (dt*16 + r16)*LD + g*8);
            bf16x8 v1 = *(const bf16x8*)(Vc + (dt*16 + r16)*LD + 32 + g*8);
            O[dt] = MFMA(aP0, v0, O[dt]);
            O[dt] = MFMA(aP1, v1, O[dt]);
        }
        __syncthreads();   // buf^1 staged by all + cur reads done -> safe to swap
    }
    #pragma unroll
    for (int dt = 0; dt < 4; ++dt)
        #pragma unroll
        for (int r = 0; r < 4; ++r) {
            int token = q0 + wave*16 + g*4 + r;
            o[(tokbase + token)*inner + hoff + dt*16 + r16] = f2bf(O[dt][r] / l_[r]);
        }
}

// ---------------- final: x[b][n][d] -> out[b][d][gh][gw] ----------------
__global__ void k_out_transpose(const float* __restrict__ x, float* __restrict__ o)
{
    __shared__ float T[32*33];
    int d0 = blockIdx.x*32, n0 = blockIdx.y*32, b = blockIdx.z;
    int t = threadIdx.x, r = t >> 5, c = t & 31;
    #pragma unroll
    for (int i = 0; i < 4; ++i)
        T[(r+i*8)*33 + c] = x[((size_t)b*1024 + n0 + r + i*8)*512 + d0 + c];
    __syncthreads();
    #pragma unroll
    for (int i = 0; i < 4; ++i)
        o[((size_t)b*512 + d0 + r + i*8)*1024 + n0 + c] = T[c*33 + (r+i*8)];
}

extern "C" void kernel_launch(void* const* d_in, const int* in_sizes, int n_in,
                              void* d_out, int out_size, void* d_ws, size_t ws_size,
                              hipStream_t stream)
{
    (void)in_sizes; (void)n_in; (void)out_size; (void)ws_size;
    const float* img     = (const float*)d_in[0];
    const float* patch_w = (const float*)d_in[1];
    const float* patch_b = (const float*)d_in[2];
    const float* pos_emb = (const float*)d_in[3];
    const float* ln1_s   = (const float*)d_in[4];
    const float* ln1_b   = (const float*)d_in[5];
    const float* ln2_s   = (const float*)d_in[6];
    const float* ln2_b   = (const float*)d_in[7];
    const float* qkv_w[3] = {(const float*)d_in[8],  (const float*)d_in[12], (const float*)d_in[16]};
    const float* out_w[3] = {(const float*)d_in[9],  (const float*)d_in[13], (const float*)d_in[17]};
    const float* out_b[3] = {(const float*)d_in[10], (const float*)d_in[14], (const float*)d_in[18]};
    const float* biasT[3] = {(const float*)d_in[11], (const float*)d_in[15], (const float*)d_in[19]};
    const float* ff_w1 = (const float*)d_in[20];
    const float* ff_b1 = (const float*)d_in[21];
    const float* ff_w2 = (const float*)d_in[22];
    const float* ff_b2 = (const float*)d_in[23];
    float* out = (float*)d_out;

    const int HS[3] = {2,4,8};
    char* ws = (char*)d_ws;
    size_t off = 0;
    auto alloc = [&](size_t bytes) -> void* {
        void* p = ws + off; off += (bytes + 255) & ~(size_t)255; return p;
    };
    u16*   pwT  = (u16*)  alloc(512ull*32768*2);
    u16*   imgb = (u16*)  alloc(4ull*128*512*512*2);
    float* part = (float*)alloc(8ull*4096*512*4);
    float* x    = (float*)alloc(4096ull*512*4);
    u16*   xn   = (u16*)  alloc(4096ull*512*2);
    u16*   qkv  = (u16*)  alloc(4096ull*1536*2);
    u16*   ob   = (u16*)  alloc(4096ull*512*2);
    u16*   mid  = (u16*)  alloc(4096ull*256*2);
    u16* qkvT[3]; u16* outT[3]; u16* f1T[3]; u16* f2T[3];
    for (int l = 0; l < 3; ++l) {
        int inner = 64*HS[l];
        qkvT[l] = (u16*)alloc((size_t)3*inner*512*2);
        outT[l] = (u16*)alloc((size_t)512*inner*2);
        f1T[l]  = (u16*)alloc((size_t)256*512*2);
        f2T[l]  = (u16*)alloc((size_t)512*256*2);
    }

    // ---- input/weight prep (once, up front) ----
    k_img_bf16<<<65536, 256, 0, stream>>>(img, imgb);
    k_prep_pw<<<dim3(1024,16), 256, 0, stream>>>(patch_w, pwT);
    PrepArgs pa;
    for (int l = 0; l < 3; ++l) {
        int inner = 64*HS[l];
        pa.src[l]   = qkv_w[l];              pa.K[l]   = 512;   pa.N[l]   = 3*inner; pa.dst[l]   = qkvT[l];
        pa.src[3+l] = out_w[l];              pa.K[3+l] = inner; pa.N[3+l] = 512;     pa.dst[3+l] = outT[l];
        pa.src[6+l] = ff_w1 + (size_t)l*512*256; pa.K[6+l] = 512; pa.N[6+l] = 256;   pa.dst[6+l] = f1T[l];
        pa.src[9+l] = ff_w2 + (size_t)l*256*512; pa.K[9+l] = 256; pa.N[9+l] = 512;   pa.dst[9+l] = f2T[l];
    }
    k_prep_weights<<<dim3(16,48,12), 256, 0, stream>>>(pa);

    // ---- patch embed: part[z] = A_z @ B_z^T ; x = pb + pe + sum_z part[z] ----
    k_gemm_patch<<<1024, 256, 0, stream>>>(imgb, pwT, part);
    k_reduce_x<<<2048, 256, 0, stream>>>(part, patch_b, pos_emb, x);

    // ---- transformer layers ----
    for (int l = 0; l < 3; ++l) {
        int h = HS[l], inner = 64*h, n3 = 3*inner;
        k_ln<<<1024, 256, 0, stream>>>(x, ln1_s + l*512, ln1_b + l*512, xn);
        k_gemm64<1><<<dim3(64, n3/64), 256, 0, stream>>>(xn, 512, qkvT[l], 512, 512,
                                                         nullptr, qkv, n3, nullptr);
        k_attn<<<dim3(16, h, 4), 256, 0, stream>>>(qkv, biasT[l], ob, h);
        k_gemm64<3><<<dim3(64, 8), 256, 0, stream>>>(ob, inner, outT[l], inner, inner,
                                                     x, nullptr, 512, out_b[l]);
        k_ln<<<1024, 256, 0, stream>>>(x, ln2_s + l*512, ln2_b + l*512, xn);
        k_gemm64<2><<<dim3(64, 4), 256, 0, stream>>>(xn, 512, f1T[l], 512, 512,
                                                     nullptr, mid, 256, ff_b1 + l*256);
        k_gemm64<3><<<dim3(64, 8), 256, 0, stream>>>(mid, 256, f2T[l], 256, 256,
                                                     x, nullptr, 512, ff_b2 + l*512);
    }
    k_out_transpose<<<dim3(16, 32, 4), 256, 0, stream>>>(x, out);
}

// Round 6
// 1289.483 us; speedup vs baseline: 1.0224x; 1.0224x over previous
//
#include <hip/hip_runtime.h>

typedef unsigned short u16;
typedef __bf16 bf16x8 __attribute__((ext_vector_type(8)));
typedef float f32x4 __attribute__((ext_vector_type(4)));

#define AS1 __attribute__((address_space(1)))
#define AS3 __attribute__((address_space(3)))
#define MFMA(a,b,c) __builtin_amdgcn_mfma_f32_16x16x32_bf16(a,b,c,0,0,0)

__device__ __forceinline__ u16 f2bf(float f) {
    union { float f; unsigned u; } x; x.f = f;
    unsigned r = x.u + 0x7fffu + ((x.u >> 16) & 1u);
    return (u16)(r >> 16);
}

// ---------------- patch_w prep: pwT[n][k'] = w[k(k')][n] bf16, k' = c*256 + p1*16 + p2 ----------------
__global__ void k_prep_pw(const float* __restrict__ in, u16* __restrict__ o)
{
    __shared__ float T[32*33];
    int kp0 = blockIdx.x*32, n0 = blockIdx.y*32;
    int t = threadIdx.x, r = t >> 5, cc = t & 31;
    #pragma unroll
    for (int i = 0; i < 4; ++i) {
        int kp = kp0 + r + i*8;
        int korig = ((kp >> 4) & 15)*2048 + (kp & 15)*128 + (kp >> 8);
        T[(r + i*8)*33 + cc] = in[(size_t)korig*512 + n0 + cc];
    }
    __syncthreads();
    #pragma unroll
    for (int i = 0; i < 4; ++i)
        o[(size_t)(n0 + r + i*8)*32768 + kp0 + cc] = f2bf(T[cc*33 + r + i*8]);
}

// ---------------- all small weight transposes in ONE launch: out[N][K] = f2bf(in[K][N]^T) ----------------
struct PrepArgs {
    const float* src[12];
    u16* dst[12];
    int K[12];
    int N[12];
};
__global__ void k_prep_weights(PrepArgs a)
{
    __shared__ float T[32*33];
    int z = blockIdx.z;
    int K = a.K[z], N = a.N[z];
    int kt = blockIdx.x*32, nt = blockIdx.y*32;
    if (kt >= K || nt >= N) return;
    const float* in = a.src[z];
    u16* o = a.dst[z];
    int t = threadIdx.x, r = t >> 5, c = t & 31;
    #pragma unroll
    for (int i = 0; i < 4; ++i)
        T[(r + i*8)*33 + c] = in[(size_t)(kt + r + i*8)*N + nt + c];
    __syncthreads();
    #pragma unroll
    for (int i = 0; i < 4; ++i)
        o[(size_t)(nt + r + i*8)*K + kt + c] = f2bf(T[c*33 + r + i*8]);
}

// ---------------- x init: patch_b + pos_emb ----------------
__global__ void k_init_x(float* __restrict__ x, const float* __restrict__ pb, const float* __restrict__ pe)
{
    int i4 = blockIdx.x*256 + threadIdx.x;
    size_t base = (size_t)i4*4;
    float4 a = *(const float4*)(pb + (base & 511));
    float4 b = *(const float4*)(pe + (base & 524287));
    float4 r = make_float4(a.x+b.x, a.y+b.y, a.z+b.z, a.w+b.w);
    *(float4*)(x + base) = r;
}

// ---------------- implicit patch-embed GEMM: x += patches(img) @ pwT^T ----------------
// Round-3 structure (single LDS buffers, 2 barriers/K-step) + REGISTER prefetch:
// A(k+1)'s 8 global_load_dwordx4 are issued before barrier-1 so their latency
// hides under barrier + ds_read + 32 MFMA; consumed (cvt+ds_write) next step.
// Same K-order as round 3 -> bit-identical accumulation.
__global__ __launch_bounds__(256) void k_gemm_patch(
    const float* __restrict__ img, const u16* __restrict__ Bt,
    float* __restrict__ Cf)
{
    __shared__ alignas(16) u16 Af[16*512];   // 16 frags x (64 lanes x 8 bf16)
    __shared__ alignas(16) u16 Bs[128*64];
    const int t = threadIdx.x;
    const int bid = blockIdx.x;
    const int xcd = bid & 7, rr = bid >> 3;
    const int nt = rr & 3, q = rr >> 2;
    const int mz = q*8 + xcd;                 // [0,256) bijective
    const int mt = mz & 31, z = mz >> 5;
    const int m0 = mt*128, n0 = nt*128;
    const int b = m0 >> 10, gh0 = (m0 & 1023) >> 5;
    const int kz = z*4096;
    const int wave = t >> 6, lane = t & 63;
    const int r16 = lane & 15, g = lane >> 4;
    const int wmh = wave >> 1;
    const int wm = wmh*64, wn = (wave & 1)*64;

    const u16* Bb = Bt + (size_t)(n0 + (t>>3))*32768 + kz + (t&7)*8;
    u16* Bsd = Bs + t*8;

    const float* imgB = img + (size_t)b*33554432 + (size_t)gh0*8192;
    int foff[4];
    #pragma unroll
    for (int i = 0; i < 4; ++i) {
        int F = i*4 + wave;
        int im_ = (F >> 1) & 3, ks = F & 1, wh = F >> 3;
        int mb = wh*64 + im_*16 + r16;
        int p1l = ks*2 + (g >> 1), p2b = (g & 1)*8;
        foff[i] = ((mb >> 5)*16 + p1l)*512 + (mb & 31)*16 + p2b;
    }

    f32x4 acc[4][4];
    const f32x4 z4 = {0.f,0.f,0.f,0.f};
    #pragma unroll
    for (int im_ = 0; im_ < 4; ++im_)
        #pragma unroll
        for (int in_ = 0; in_ < 4; ++in_) acc[im_][in_] = z4;

    // preload A(k=0) into registers
    float4 pv0[4], pv1[4];
    {
        const float* srcK = imgB + (size_t)(kz >> 8)*262144 + ((kz >> 4) & 15)*512;
        #pragma unroll
        for (int i = 0; i < 4; ++i) {
            const float* s = srcK + foff[i];
            pv0[i] = *(const float4*)s;
            pv1[i] = *(const float4*)(s + 4);
        }
    }

    for (int k = 0; k < 4096; k += 64) {
        #pragma unroll
        for (int i = 0; i < 4; ++i)
            __builtin_amdgcn_global_load_lds((AS1 void*)(Bb + (size_t)i*32*32768 + k), (AS3 void*)(Bsd + i*2048), 16, 0, 0);
        // cvt + ds_write A(k) from the prefetched registers
        #pragma unroll
        for (int i = 0; i < 4; ++i) {
            bf16x8 pk;
            pk[0] = (__bf16)pv0[i].x; pk[1] = (__bf16)pv0[i].y; pk[2] = (__bf16)pv0[i].z; pk[3] = (__bf16)pv0[i].w;
            pk[4] = (__bf16)pv1[i].x; pk[5] = (__bf16)pv1[i].y; pk[6] = (__bf16)pv1[i].z; pk[7] = (__bf16)pv1[i].w;
            *(bf16x8*)(Af + (i*4 + wave)*512 + lane*8) = pk;
        }
        // issue A(k+1) loads now: latency hides under barrier + ds_read + MFMA
        if (k + 64 < 4096) {
            const int koff = kz + k + 64;
            const float* srcK = imgB + (size_t)(koff >> 8)*262144 + ((koff >> 4) & 15)*512;
            #pragma unroll
            for (int i = 0; i < 4; ++i) {
                const float* s = srcK + foff[i];
                pv0[i] = *(const float4*)s;
                pv1[i] = *(const float4*)(s + 4);
            }
        }
        __syncthreads();
        #pragma unroll
        for (int kk = 0; kk < 64; kk += 32) {
            const int ks = kk >> 5;
            bf16x8 af[4], bfr[4];
            #pragma unroll
            for (int im_ = 0; im_ < 4; ++im_)
                af[im_] = *(const bf16x8*)(Af + (wmh*8 + im_*2 + ks)*512 + lane*8);
            #pragma unroll
            for (int in_ = 0; in_ < 4; ++in_)
                bfr[in_] = *(const bf16x8*)(Bs + (wn + in_*16 + r16)*64 + kk + g*8);
            #pragma unroll
            for (int im_ = 0; im_ < 4; ++im_)
                #pragma unroll
                for (int in_ = 0; in_ < 4; ++in_)
                    acc[im_][in_] = MFMA(af[im_], bfr[in_], acc[im_][in_]);
        }
        __syncthreads();
    }
    #pragma unroll
    for (int im_ = 0; im_ < 4; ++im_) {
        int row = m0 + wm + im_*16 + g*4;
        #pragma unroll
        for (int in_ = 0; in_ < 4; ++in_) {
            int col = n0 + wn + in_*16 + r16;
            #pragma unroll
            for (int r4 = 0; r4 < 4; ++r4)
                __hip_atomic_fetch_add(&Cf[(size_t)(row + r4)*512 + col], acc[im_][in_][r4],
                                       __ATOMIC_RELAXED, __HIP_MEMORY_SCOPE_AGENT);
        }
    }
}

// ---------------- LayerNorm: 4 rows per 256-thread block (1 wave/row), fp32 in -> bf16 out ----------------
__global__ __launch_bounds__(256) void k_ln(const float* __restrict__ x, const float* __restrict__ sc,
                                            const float* __restrict__ bi, u16* __restrict__ o)
{
    int row = blockIdx.x*4 + (threadIdx.x >> 6), lane = threadIdx.x & 63;
    const float* xr = x + (size_t)row*512 + lane*8;
    float4 v0 = *(const float4*)xr;
    float4 v1 = *(const float4*)(xr + 4);
    float vv[8] = {v0.x,v0.y,v0.z,v0.w,v1.x,v1.y,v1.z,v1.w};
    float sum = 0.f, sq = 0.f;
    #pragma unroll
    for (int i = 0; i < 8; ++i) { sum += vv[i]; sq += vv[i]*vv[i]; }
    #pragma unroll
    for (int m = 1; m < 64; m <<= 1) { sum += __shfl_xor(sum, m, 64); sq += __shfl_xor(sq, m, 64); }
    float mean = sum * (1.f/512.f);
    float var  = sq  * (1.f/512.f) - mean*mean;
    float rstd = rsqrtf(var + 1e-5f);
    int d = lane*8;
    union { u16 u[8]; uint4 v; } pk;
    #pragma unroll
    for (int i = 0; i < 8; ++i) pk.u[i] = f2bf((vv[i]-mean)*rstd*sc[d+i] + bi[d+i]);
    *(uint4*)(o + (size_t)row*512 + d) = pk.v;
}

// ---------------- small-N bf16 GEMM: 64x64x64 tiles, 4 waves, 2x2 frags/wave ----------------
// EPI: 1 = bf16 store, 2 = gelu(acc+bias) bf16, 3 = Cf += acc+bias
template<int EPI>
__global__ __launch_bounds__(256) void k_gemm64(
    const u16* __restrict__ A, int lda,
    const u16* __restrict__ Bt, int ldb,
    int Kblk,
    float* __restrict__ Cf, u16* __restrict__ Cb, int ldc,
    const float* __restrict__ bias)
{
    __shared__ alignas(16) u16 As[64*64];
    __shared__ alignas(16) u16 Bs[64*64];
    const int t = threadIdx.x;
    const int m0 = blockIdx.x*64, n0 = blockIdx.y*64;
    const int wave = t >> 6, lane = t & 63;
    const int wm = (wave >> 1)*32, wn = (wave & 1)*32;
    const int r16 = lane & 15, g = lane >> 4;
    const u16* Ab = A + (size_t)(m0 + (t>>3))*lda + (t&7)*8;
    const u16* Bb = Bt + (size_t)(n0 + (t>>3))*ldb + (t&7)*8;
    u16* Asd = As + t*8;
    u16* Bsd = Bs + t*8;
    f32x4 acc[2][2];
    const f32x4 z4 = {0.f,0.f,0.f,0.f};
    #pragma unroll
    for (int im = 0; im < 2; ++im)
        #pragma unroll
        for (int in_ = 0; in_ < 2; ++in_) acc[im][in_] = z4;

    for (int k = 0; k < Kblk; k += 64) {
        #pragma unroll
        for (int i = 0; i < 2; ++i) {
            __builtin_amdgcn_global_load_lds((AS1 void*)(Ab + (size_t)i*32*lda + k), (AS3 void*)(Asd + i*2048), 16, 0, 0);
            __builtin_amdgcn_global_load_lds((AS1 void*)(Bb + (size_t)i*32*ldb + k), (AS3 void*)(Bsd + i*2048), 16, 0, 0);
        }
        __syncthreads();
        #pragma unroll
        for (int kk = 0; kk < 64; kk += 32) {
            bf16x8 af[2], bfr[2];
            #pragma unroll
            for (int im = 0; im < 2; ++im)
                af[im] = *(const bf16x8*)(As + (wm + im*16 + r16)*64 + kk + g*8);
            #pragma unroll
            for (int in_ = 0; in_ < 2; ++in_)
                bfr[in_] = *(const bf16x8*)(Bs + (wn + in_*16 + r16)*64 + kk + g*8);
            #pragma unroll
            for (int im = 0; im < 2; ++im)
                #pragma unroll
                for (int in_ = 0; in_ < 2; ++in_)
                    acc[im][in_] = MFMA(af[im], bfr[in_], acc[im][in_]);
        }
        __syncthreads();
    }
    #pragma unroll
    for (int im = 0; im < 2; ++im) {
        int row = m0 + wm + im*16 + g*4;
        #pragma unroll
        for (int in_ = 0; in_ < 2; ++in_) {
            int col = n0 + wn + in_*16 + r16;
            #pragma unroll
            for (int r = 0; r < 4; ++r) {
                float v = acc[im][in_][r];
                size_t idx = (size_t)(row + r)*ldc + col;
                if constexpr (EPI == 1) {
                    Cb[idx] = f2bf(v);
                } else if constexpr (EPI == 2) {
                    float xv = v + bias[col];
                    Cb[idx] = f2bf(0.5f*xv*(1.f + erff(xv*0.70710678118654752f)));
                } else {
                    Cf[idx] += v + bias[col];
                }
            }
        }
    }
}

// ---------------- flash attention with relative position bias ----------------
// K/V double-buffered in LDS, ONE barrier per kt-tile (stage kt+1 at loop top).
__global__ __launch_bounds__(256) void k_attn(
    const u16* __restrict__ qkv, const float* __restrict__ bt,
    u16* __restrict__ o, int H)
{
    const int LD = 80;
    __shared__ alignas(16) u16 Qs[64*80];
    __shared__ alignas(16) u16 Ks[2][64*80], Vs[2][64*80];
    __shared__ alignas(16) u16 Ps[4][16*80];
    const int inner = H*64, s3 = 3*inner;
    const int qt = blockIdx.x, head = blockIdx.y, b = blockIdx.z;
    const int t = threadIdx.x, wave = t >> 6, lane = t & 63;
    const int r16 = lane & 15, g = lane >> 4;
    const int q0 = qt*64;
    const size_t tokbase = (size_t)b*1024;
    const int hoff = head*64;

    #pragma unroll
    for (int it = 0; it < 2; ++it) {
        int flat = it*256 + t, r = flat >> 3, d0 = (flat & 7)*8;
        uint4 v = *(const uint4*)(qkv + (tokbase + q0 + r)*s3 + hoff + d0);
        *(uint4*)(Qs + r*LD + d0) = v;
    }

    auto stageKV = [&](int kt, int bufi) {
        const int key0 = kt*64;
        #pragma unroll
        for (int it = 0; it < 2; ++it) {
            int flat = it*256 + t, r = flat >> 3, d0 = (flat & 7)*8;
            uint4 v = *(const uint4*)(qkv + (tokbase + key0 + r)*s3 + inner + hoff + d0);
            *(uint4*)(Ks[bufi] + r*LD + d0) = v;
        }
        #pragma unroll
        for (int it = 0; it < 2; ++it) {
            int flat = it*256 + t, key = flat & 63, d0 = (flat >> 6)*8;
            uint4 v = *(const uint4*)(qkv + (tokbase + key0 + key)*s3 + 2*inner + hoff + d0);
            const u16* pv = (const u16*)&v;
            #pragma unroll
            for (int i = 0; i < 8; ++i) Vs[bufi][(d0+i)*LD + key] = pv[i];
        }
    };

    stageKV(0, 0);
    __syncthreads();

    bf16x8 aQ0 = *(const bf16x8*)(Qs + (wave*16 + r16)*LD + g*8);
    bf16x8 aQ1 = *(const bf16x8*)(Qs + (wave*16 + r16)*LD + 32 + g*8);

    float m_[4], l_[4];
    f32x4 O[4];
    const f32x4 z4 = {0.f,0.f,0.f,0.f};
    #pragma unroll
    for (int r = 0; r < 4; ++r) { m_[r] = -1e30f; l_[r] = 0.f; O[r] = z4; }
    const int qg_base = q0 + wave*16 + g*4;

    for (int kt = 0; kt < 16; ++kt) {
        const int cur = kt & 1;
        if (kt < 15) stageKV(kt + 1, cur ^ 1);
        const int key0 = kt*64;
        const u16* Kc = Ks[cur];
        const u16* Vc = Vs[cur];

        float Sv[4][4];
        #pragma unroll
        for (int kb = 0; kb < 4; ++kb) {
            bf16x8 k0f = *(const bf16x8*)(Kc + (kb*16 + r16)*LD + g*8);
            bf16x8 k1f = *(const bf16x8*)(Kc + (kb*16 + r16)*LD + 32 + g*8);
            f32x4 S = z4;
            S = MFMA(aQ0, k0f, S);
            S = MFMA(aQ1, k1f, S);
            int keyg = key0 + kb*16 + r16;
            int kgh = keyg >> 5, kgw = keyg & 31;
            #pragma unroll
            for (int r = 0; r < 4; ++r) {
                int qg = qg_base + r;
                int rel = ((qg >> 5) - kgh + 31)*63 + ((qg & 31) - kgw + 31);
                Sv[kb][r] = S[r]*0.125f + bt[rel*H + head];
            }
        }
        float mx[4], al[4], ps[4];
        #pragma unroll
        for (int r = 0; r < 4; ++r)
            mx[r] = fmaxf(fmaxf(Sv[0][r], Sv[1][r]), fmaxf(Sv[2][r], Sv[3][r]));
        #pragma unroll
        for (int msk = 1; msk < 16; msk <<= 1)
            #pragma unroll
            for (int r = 0; r < 4; ++r) mx[r] = fmaxf(mx[r], __shfl_xor(mx[r], msk, 64));
        #pragma unroll
        for (int r = 0; r < 4; ++r) {
            float nm = fmaxf(m_[r], mx[r]);
            al[r] = __expf(m_[r] - nm);
            m_[r] = nm;
            ps[r] = 0.f;
        }
        #pragma unroll
        for (int kb = 0; kb < 4; ++kb)
            #pragma unroll
            for (int r = 0; r < 4; ++r) {
                float p = __expf(Sv[kb][r] - m_[r]);
                Sv[kb][r] = p;
                ps[r] += p;
            }
        #pragma unroll
        for (int msk = 1; msk < 16; msk <<= 1)
            #pragma unroll
            for (int r = 0; r < 4; ++r) ps[r] += __shfl_xor(ps[r], msk, 64);
        #pragma unroll
        for (int r = 0; r < 4; ++r) l_[r] = l_[r]*al[r] + ps[r];
        #pragma unroll
        for (int kb = 0; kb < 4; ++kb)
            #pragma unroll
            for (int r = 0; r < 4; ++r)
                Ps[wave][(g*4 + r)*LD + kb*16 + r16] = f2bf(Sv[kb][r]);
        #pragma unroll
        for (int dt = 0; dt < 4; ++dt)
            #pragma unroll
            for (int r = 0; r < 4; ++r) O[dt][r] = O[dt][r]*al[r];
        // Ps[wave] write->read is same-wave: compiler's lgkmcnt wait suffices, no barrier.
        bf16x8 aP0 = *(const bf16x8*)(Ps[wave] + r16*LD + g*8);
        bf16x8 aP1 = *(const bf16x8*)(Ps[wave] + r16*LD + 32 + g*8);
        #pragma unroll
        for (int dt = 0; dt < 4; ++dt) {
            bf16x8 v0 = *(const bf16x8*)(Vc + (dt*16 + r16)*LD + g*8);
            bf16x8 v1 = *(const bf16x8*)(Vc + (dt*16 + r16)*LD + 32 + g*8);
            O[dt] = MFMA(aP0, v0, O[dt]);
            O[dt] = MFMA(aP1, v1, O[dt]);
        }
        __syncthreads();   // buf^1 staged by all + cur reads done -> safe to swap
    }
    #pragma unroll
    for (int dt = 0; dt < 4; ++dt)
        #pragma unroll
        for (int r = 0; r < 4; ++r) {
            int token = q0 + wave*16 + g*4 + r;
            o[(tokbase + token)*inner + hoff + dt*16 + r16] = f2bf(O[dt][r] / l_[r]);
        }
}

// ---------------- final: x[b][n][d] -> out[b][d][gh][gw] ----------------
__global__ void k_out_transpose(const float* __restrict__ x, float* __restrict__ o)
{
    __shared__ float T[32*33];
    int d0 = blockIdx.x*32, n0 = blockIdx.y*32, b = blockIdx.z;
    int t = threadIdx.x, r = t >> 5, c = t & 31;
    #pragma unroll
    for (int i = 0; i < 4; ++i)
        T[(r+i*8)*33 + c] = x[((size_t)b*1024 + n0 + r + i*8)*512 + d0 + c];
    __syncthreads();
    #pragma unroll
    for (int i = 0; i < 4; ++i)
        o[((size_t)b*512 + d0 + r + i*8)*1024 + n0 + c] = T[c*33 + (r+i*8)];
}

extern "C" void kernel_launch(void* const* d_in, const int* in_sizes, int n_in,
                              void* d_out, int out_size, void* d_ws, size_t ws_size,
                              hipStream_t stream)
{
    (void)in_sizes; (void)n_in; (void)out_size; (void)ws_size;
    const float* img     = (const float*)d_in[0];
    const float* patch_w = (const float*)d_in[1];
    const float* patch_b = (const float*)d_in[2];
    const float* pos_emb = (const float*)d_in[3];
    const float* ln1_s   = (const float*)d_in[4];
    const float* ln1_b   = (const float*)d_in[5];
    const float* ln2_s   = (const float*)d_in[6];
    const float* ln2_b   = (const float*)d_in[7];
    const float* qkv_w[3] = {(const float*)d_in[8],  (const float*)d_in[12], (const float*)d_in[16]};
    const float* out_w[3] = {(const float*)d_in[9],  (const float*)d_in[13], (const float*)d_in[17]};
    const float* out_b[3] = {(const float*)d_in[10], (const float*)d_in[14], (const float*)d_in[18]};
    const float* biasT[3] = {(const float*)d_in[11], (const float*)d_in[15], (const float*)d_in[19]};
    const float* ff_w1 = (const float*)d_in[20];
    const float* ff_b1 = (const float*)d_in[21];
    const float* ff_w2 = (const float*)d_in[22];
    const float* ff_b2 = (const float*)d_in[23];
    float* out = (float*)d_out;

    const int HS[3] = {2,4,8};
    char* ws = (char*)d_ws;
    size_t off = 0;
    auto alloc = [&](size_t bytes) -> void* {
        void* p = ws + off; off += (bytes + 255) & ~(size_t)255; return p;
    };
    u16*   pwT  = (u16*)  alloc(512ull*32768*2);
    float* x    = (float*)alloc(4096ull*512*4);
    u16*   xn   = (u16*)  alloc(4096ull*512*2);
    u16*   qkv  = (u16*)  alloc(4096ull*1536*2);
    u16*   ob   = (u16*)  alloc(4096ull*512*2);
    u16*   mid  = (u16*)  alloc(4096ull*256*2);
    u16* qkvT[3]; u16* outT[3]; u16* f1T[3]; u16* f2T[3];
    for (int l = 0; l < 3; ++l) {
        int inner = 64*HS[l];
        qkvT[l] = (u16*)alloc((size_t)3*inner*512*2);
        outT[l] = (u16*)alloc((size_t)512*inner*2);
        f1T[l]  = (u16*)alloc((size_t)256*512*2);
        f2T[l]  = (u16*)alloc((size_t)512*256*2);
    }

    // ---- weight prep (once, up front) ----
    k_prep_pw<<<dim3(1024,16), 256, 0, stream>>>(patch_w, pwT);
    PrepArgs pa;
    for (int l = 0; l < 3; ++l) {
        int inner = 64*HS[l];
        pa.src[l]   = qkv_w[l];              pa.K[l]   = 512;   pa.N[l]   = 3*inner; pa.dst[l]   = qkvT[l];
        pa.src[3+l] = out_w[l];              pa.K[3+l] = inner; pa.N[3+l] = 512;     pa.dst[3+l] = outT[l];
        pa.src[6+l] = ff_w1 + (size_t)l*512*256; pa.K[6+l] = 512; pa.N[6+l] = 256;   pa.dst[6+l] = f1T[l];
        pa.src[9+l] = ff_w2 + (size_t)l*256*512; pa.K[9+l] = 256; pa.N[9+l] = 512;   pa.dst[9+l] = f2T[l];
    }
    k_prep_weights<<<dim3(16,48,12), 256, 0, stream>>>(pa);

    // ---- patch embed: x = patches(img) @ pwT^T + patch_b + pos_emb ----
    k_init_x<<<2048, 256, 0, stream>>>(x, patch_b, pos_emb);
    k_gemm_patch<<<1024, 256, 0, stream>>>(img, pwT, x);

    // ---- transformer layers ----
    for (int l = 0; l < 3; ++l) {
        int h = HS[l], inner = 64*h, n3 = 3*inner;
        k_ln<<<1024, 256, 0, stream>>>(x, ln1_s + l*512, ln1_b + l*512, xn);
        k_gemm64<1><<<dim3(64, n3/64), 256, 0, stream>>>(xn, 512, qkvT[l], 512, 512,
                                                         nullptr, qkv, n3, nullptr);
        k_attn<<<dim3(16, h, 4), 256, 0, stream>>>(qkv, biasT[l], ob, h);
        k_gemm64<3><<<dim3(64, 8), 256, 0, stream>>>(ob, inner, outT[l], inner, inner,
                                                     x, nullptr, 512, out_b[l]);
        k_ln<<<1024, 256, 0, stream>>>(x, ln2_s + l*512, ln2_b + l*512, xn);
        k_gemm64<2><<<dim3(64, 4), 256, 0, stream>>>(xn, 512, f1T[l], 512, 512,
                                                     nullptr, mid, 256, ff_b1 + l*256);
        k_gemm64<3><<<dim3(64, 8), 256, 0, stream>>>(mid, 256, f2T[l], 256, 256,
                                                     x, nullptr, 512, ff_b2 + l*512);
    }
    k_out_transpose<<<dim3(16, 32, 4), 256, 0, stream>>>(x, out);
}

// Round 7
// 1228.076 us; speedup vs baseline: 1.0736x; 1.0500x over previous
//
#include <hip/hip_runtime.h>

typedef unsigned short u16;
typedef __bf16 bf16x8 __attribute__((ext_vector_type(8)));
typedef float f32x4 __attribute__((ext_vector_type(4)));

#define AS1 __attribute__((address_space(1)))
#define AS3 __attribute__((address_space(3)))
#define MFMA(a,b,c) __builtin_amdgcn_mfma_f32_16x16x32_bf16(a,b,c,0,0,0)

__device__ __forceinline__ u16 f2bf(float f) {
    union { float f; unsigned u; } x; x.f = f;
    unsigned r = x.u + 0x7fffu + ((x.u >> 16) & 1u);
    return (u16)(r >> 16);
}

// ---------------- patch_w prep: pwT[n][k'] = w[k(k')][n] bf16, k' = c*256 + p1*16 + p2 ----------------
__global__ void k_prep_pw(const float* __restrict__ in, u16* __restrict__ o)
{
    __shared__ float T[32*33];
    int kp0 = blockIdx.x*32, n0 = blockIdx.y*32;
    int t = threadIdx.x, r = t >> 5, cc = t & 31;
    #pragma unroll
    for (int i = 0; i < 4; ++i) {
        int kp = kp0 + r + i*8;
        int korig = ((kp >> 4) & 15)*2048 + (kp & 15)*128 + (kp >> 8);
        T[(r + i*8)*33 + cc] = in[(size_t)korig*512 + n0 + cc];
    }
    __syncthreads();
    #pragma unroll
    for (int i = 0; i < 4; ++i)
        o[(size_t)(n0 + r + i*8)*32768 + kp0 + cc] = f2bf(T[cc*33 + r + i*8]);
}

// ---------------- all small weight transposes in ONE launch: out[N][K] = f2bf(in[K][N]^T) ----------------
struct PrepArgs {
    const float* src[12];
    u16* dst[12];
    int K[12];
    int N[12];
};
__global__ void k_prep_weights(PrepArgs a)
{
    __shared__ float T[32*33];
    int z = blockIdx.z;
    int K = a.K[z], N = a.N[z];
    int kt = blockIdx.x*32, nt = blockIdx.y*32;
    if (kt >= K || nt >= N) return;
    const float* in = a.src[z];
    u16* o = a.dst[z];
    int t = threadIdx.x, r = t >> 5, c = t & 31;
    #pragma unroll
    for (int i = 0; i < 4; ++i)
        T[(r + i*8)*33 + c] = in[(size_t)(kt + r + i*8)*N + nt + c];
    __syncthreads();
    #pragma unroll
    for (int i = 0; i < 4; ++i)
        o[(size_t)(nt + r + i*8)*K + kt + c] = f2bf(T[c*33 + r + i*8]);
}

// ---------------- x init: patch_b + pos_emb ----------------
__global__ void k_init_x(float* __restrict__ x, const float* __restrict__ pb, const float* __restrict__ pe)
{
    int i4 = blockIdx.x*256 + threadIdx.x;
    size_t base = (size_t)i4*4;
    float4 a = *(const float4*)(pb + (base & 511));
    float4 b = *(const float4*)(pe + (base & 524287));
    float4 r = make_float4(a.x+b.x, a.y+b.y, a.z+b.z, a.w+b.w);
    *(float4*)(x + base) = r;
}

// ---------------- implicit patch-embed GEMM: x += patches(img) @ pwT^T ----------------
// Round-3 schedule (loads at top, consume immediately, 2 barriers/K-step).
// T2 swizzle on Bs (rule #21 both-sides): global SOURCE chunk XOR'd so linear
// global_load_lds dest holds swizzled rows; ds_read applies the same XOR.
// Kills the 16-way bank conflict on stride-128B Bs rows (25M conflicts measured).
__global__ __launch_bounds__(256) void k_gemm_patch(
    const float* __restrict__ img, const u16* __restrict__ Bt,
    float* __restrict__ Cf)
{
    __shared__ alignas(16) u16 Af[16*512];   // 16 frags x (64 lanes x 8 bf16), linear reads
    __shared__ alignas(16) u16 Bs[128*64];   // swizzled storage
    const int t = threadIdx.x;
    const int bid = blockIdx.x;
    const int xcd = bid & 7, rr = bid >> 3;
    const int nt = rr & 3, q = rr >> 2;
    const int mz = q*8 + xcd;                 // [0,256) bijective
    const int mt = mz & 31, z = mz >> 5;
    const int m0 = mt*128, n0 = nt*128;
    const int b = m0 >> 10, gh0 = (m0 & 1023) >> 5;
    const int kz = z*4096;
    const int wave = t >> 6, lane = t & 63;
    const int r16 = lane & 15, g = lane >> 4;
    const int wmh = wave >> 1;
    const int wm = wmh*64, wn = (wave & 1)*64;

    // swizzled source: chunk (t&7) -> (t&7) ^ (row&7), row = t>>3 (mod 8 invariant under +32i)
    const u16* Bb = Bt + (size_t)(n0 + (t>>3))*32768 + kz + (size_t)(((t&7) ^ ((t>>3)&7))*8);
    u16* Bsd = Bs + t*8;

    const float* imgB = img + (size_t)b*33554432 + (size_t)gh0*8192;
    int foff[4];
    #pragma unroll
    for (int i = 0; i < 4; ++i) {
        int F = i*4 + wave;
        int im_ = (F >> 1) & 3, ks = F & 1, wh = F >> 3;
        int mb = wh*64 + im_*16 + r16;
        int p1l = ks*2 + (g >> 1), p2b = (g & 1)*8;
        foff[i] = ((mb >> 5)*16 + p1l)*512 + (mb & 31)*16 + p2b;
    }

    f32x4 acc[4][4];
    const f32x4 z4 = {0.f,0.f,0.f,0.f};
    #pragma unroll
    for (int im_ = 0; im_ < 4; ++im_)
        #pragma unroll
        for (int in_ = 0; in_ < 4; ++in_) acc[im_][in_] = z4;

    for (int k = 0; k < 4096; k += 64) {
        const int koff = kz + k;
        const float* srcK = imgB + (size_t)(koff >> 8)*262144 + ((koff >> 4) & 15)*512;
        #pragma unroll
        for (int i = 0; i < 4; ++i)
            __builtin_amdgcn_global_load_lds((AS1 void*)(Bb + (size_t)i*32*32768 + k), (AS3 void*)(Bsd + i*2048), 16, 0, 0);
        #pragma unroll
        for (int i = 0; i < 4; ++i) {
            const float* s = srcK + foff[i];
            float4 v0 = *(const float4*)s;
            float4 v1 = *(const float4*)(s + 4);
            bf16x8 pk;
            pk[0] = (__bf16)v0.x; pk[1] = (__bf16)v0.y; pk[2] = (__bf16)v0.z; pk[3] = (__bf16)v0.w;
            pk[4] = (__bf16)v1.x; pk[5] = (__bf16)v1.y; pk[6] = (__bf16)v1.z; pk[7] = (__bf16)v1.w;
            *(bf16x8*)(Af + (i*4 + wave)*512 + lane*8) = pk;
        }
        __syncthreads();
        #pragma unroll
        for (int kk = 0; kk < 64; kk += 32) {
            const int ks = kk >> 5;
            bf16x8 af[4], bfr[4];
            #pragma unroll
            for (int im_ = 0; im_ < 4; ++im_)
                af[im_] = *(const bf16x8*)(Af + (wmh*8 + im_*2 + ks)*512 + lane*8);
            #pragma unroll
            for (int in_ = 0; in_ < 4; ++in_)
                bfr[in_] = *(const bf16x8*)(Bs + (wn + in_*16 + r16)*64 + ((ks*4 + g) ^ (r16 & 7))*8);
            #pragma unroll
            for (int im_ = 0; im_ < 4; ++im_)
                #pragma unroll
                for (int in_ = 0; in_ < 4; ++in_)
                    acc[im_][in_] = MFMA(af[im_], bfr[in_], acc[im_][in_]);
        }
        __syncthreads();
    }
    #pragma unroll
    for (int im_ = 0; im_ < 4; ++im_) {
        int row = m0 + wm + im_*16 + g*4;
        #pragma unroll
        for (int in_ = 0; in_ < 4; ++in_) {
            int col = n0 + wn + in_*16 + r16;
            #pragma unroll
            for (int r4 = 0; r4 < 4; ++r4)
                __hip_atomic_fetch_add(&Cf[(size_t)(row + r4)*512 + col], acc[im_][in_][r4],
                                       __ATOMIC_RELAXED, __HIP_MEMORY_SCOPE_AGENT);
        }
    }
}

// ---------------- LayerNorm: 4 rows per 256-thread block (1 wave/row), fp32 in -> bf16 out ----------------
__global__ __launch_bounds__(256) void k_ln(const float* __restrict__ x, const float* __restrict__ sc,
                                            const float* __restrict__ bi, u16* __restrict__ o)
{
    int row = blockIdx.x*4 + (threadIdx.x >> 6), lane = threadIdx.x & 63;
    const float* xr = x + (size_t)row*512 + lane*8;
    float4 v0 = *(const float4*)xr;
    float4 v1 = *(const float4*)(xr + 4);
    float vv[8] = {v0.x,v0.y,v0.z,v0.w,v1.x,v1.y,v1.z,v1.w};
    float sum = 0.f, sq = 0.f;
    #pragma unroll
    for (int i = 0; i < 8; ++i) { sum += vv[i]; sq += vv[i]*vv[i]; }
    #pragma unroll
    for (int m = 1; m < 64; m <<= 1) { sum += __shfl_xor(sum, m, 64); sq += __shfl_xor(sq, m, 64); }
    float mean = sum * (1.f/512.f);
    float var  = sq  * (1.f/512.f) - mean*mean;
    float rstd = rsqrtf(var + 1e-5f);
    int d = lane*8;
    union { u16 u[8]; uint4 v; } pk;
    #pragma unroll
    for (int i = 0; i < 8; ++i) pk.u[i] = f2bf((vv[i]-mean)*rstd*sc[d+i] + bi[d+i]);
    *(uint4*)(o + (size_t)row*512 + d) = pk.v;
}

// ---------------- small-N bf16 GEMM: 64x64x64 tiles, 4 waves, 2x2 frags/wave ----------------
// T2 swizzle on BOTH As and Bs (same stride-128B 16-way conflict as patch Bs):
// swizzled global source chunk + XOR'd ds_read chunk. Bit-identical results.
// EPI: 1 = bf16 store, 2 = gelu(acc+bias) bf16, 3 = Cf += acc+bias
template<int EPI>
__global__ __launch_bounds__(256) void k_gemm64(
    const u16* __restrict__ A, int lda,
    const u16* __restrict__ Bt, int ldb,
    int Kblk,
    float* __restrict__ Cf, u16* __restrict__ Cb, int ldc,
    const float* __restrict__ bias)
{
    __shared__ alignas(16) u16 As[64*64];
    __shared__ alignas(16) u16 Bs[64*64];
    const int t = threadIdx.x;
    const int m0 = blockIdx.x*64, n0 = blockIdx.y*64;
    const int wave = t >> 6, lane = t & 63;
    const int wm = (wave >> 1)*32, wn = (wave & 1)*32;
    const int r16 = lane & 15, g = lane >> 4;
    const int swz = ((t&7) ^ ((t>>3)&7))*8;
    const u16* Ab = A + (size_t)(m0 + (t>>3))*lda + swz;
    const u16* Bb = Bt + (size_t)(n0 + (t>>3))*ldb + swz;
    u16* Asd = As + t*8;
    u16* Bsd = Bs + t*8;
    f32x4 acc[2][2];
    const f32x4 z4 = {0.f,0.f,0.f,0.f};
    #pragma unroll
    for (int im = 0; im < 2; ++im)
        #pragma unroll
        for (int in_ = 0; in_ < 2; ++in_) acc[im][in_] = z4;

    for (int k = 0; k < Kblk; k += 64) {
        #pragma unroll
        for (int i = 0; i < 2; ++i) {
            __builtin_amdgcn_global_load_lds((AS1 void*)(Ab + (size_t)i*32*lda + k), (AS3 void*)(Asd + i*2048), 16, 0, 0);
            __builtin_amdgcn_global_load_lds((AS1 void*)(Bb + (size_t)i*32*ldb + k), (AS3 void*)(Bsd + i*2048), 16, 0, 0);
        }
        __syncthreads();
        #pragma unroll
        for (int kk = 0; kk < 64; kk += 32) {
            const int ks = kk >> 5;
            const int rchunk = ((ks*4 + g) ^ (r16 & 7))*8;
            bf16x8 af[2], bfr[2];
            #pragma unroll
            for (int im = 0; im < 2; ++im)
                af[im] = *(const bf16x8*)(As + (wm + im*16 + r16)*64 + rchunk);
            #pragma unroll
            for (int in_ = 0; in_ < 2; ++in_)
                bfr[in_] = *(const bf16x8*)(Bs + (wn + in_*16 + r16)*64 + rchunk);
            #pragma unroll
            for (int im = 0; im < 2; ++im)
                #pragma unroll
                for (int in_ = 0; in_ < 2; ++in_)
                    acc[im][in_] = MFMA(af[im], bfr[in_], acc[im][in_]);
        }
        __syncthreads();
    }
    #pragma unroll
    for (int im = 0; im < 2; ++im) {
        int row = m0 + wm + im*16 + g*4;
        #pragma unroll
        for (int in_ = 0; in_ < 2; ++in_) {
            int col = n0 + wn + in_*16 + r16;
            #pragma unroll
            for (int r = 0; r < 4; ++r) {
                float v = acc[im][in_][r];
                size_t idx = (size_t)(row + r)*ldc + col;
                if constexpr (EPI == 1) {
                    Cb[idx] = f2bf(v);
                } else if constexpr (EPI == 2) {
                    float xv = v + bias[col];
                    Cb[idx] = f2bf(0.5f*xv*(1.f + erff(xv*0.70710678118654752f)));
                } else {
                    Cf[idx] += v + bias[col];
                }
            }
        }
    }
}

// ---------------- flash attention with relative position bias ----------------
// K/V double-buffered in LDS, ONE barrier per kt-tile (stage kt+1 at loop top).
__global__ __launch_bounds__(256) void k_attn(
    const u16* __restrict__ qkv, const float* __restrict__ bt,
    u16* __restrict__ o, int H)
{
    const int LD = 80;
    __shared__ alignas(16) u16 Qs[64*80];
    __shared__ alignas(16) u16 Ks[2][64*80], Vs[2][64*80];
    __shared__ alignas(16) u16 Ps[4][16*80];
    const int inner = H*64, s3 = 3*inner;
    const int qt = blockIdx.x, head = blockIdx.y, b = blockIdx.z;
    const int t = threadIdx.x, wave = t >> 6, lane = t & 63;
    const int r16 = lane & 15, g = lane >> 4;
    const int q0 = qt*64;
    const size_t tokbase = (size_t)b*1024;
    const int hoff = head*64;

    #pragma unroll
    for (int it = 0; it < 2; ++it) {
        int flat = it*256 + t, r = flat >> 3, d0 = (flat & 7)*8;
        uint4 v = *(const uint4*)(qkv + (tokbase + q0 + r)*s3 + hoff + d0);
        *(uint4*)(Qs + r*LD + d0) = v;
    }

    auto stageKV = [&](int kt, int bufi) {
        const int key0 = kt*64;
        #pragma unroll
        for (int it = 0; it < 2; ++it) {
            int flat = it*256 + t, r = flat >> 3, d0 = (flat & 7)*8;
            uint4 v = *(const uint4*)(qkv + (tokbase + key0 + r)*s3 + inner + hoff + d0);
            *(uint4*)(Ks[bufi] + r*LD + d0) = v;
        }
        #pragma unroll
        for (int it = 0; it < 2; ++it) {
            int flat = it*256 + t, key = flat & 63, d0 = (flat >> 6)*8;
            uint4 v = *(const uint4*)(qkv + (tokbase + key0 + key)*s3 + 2*inner + hoff + d0);
            const u16* pv = (const u16*)&v;
            #pragma unroll
            for (int i = 0; i < 8; ++i) Vs[bufi][(d0+i)*LD + key] = pv[i];
        }
    };

    stageKV(0, 0);
    __syncthreads();

    bf16x8 aQ0 = *(const bf16x8*)(Qs + (wave*16 + r16)*LD + g*8);
    bf16x8 aQ1 = *(const bf16x8*)(Qs + (wave*16 + r16)*LD + 32 + g*8);

    float m_[4], l_[4];
    f32x4 O[4];
    const f32x4 z4 = {0.f,0.f,0.f,0.f};
    #pragma unroll
    for (int r = 0; r < 4; ++r) { m_[r] = -1e30f; l_[r] = 0.f; O[r] = z4; }
    const int qg_base = q0 + wave*16 + g*4;

    for (int kt = 0; kt < 16; ++kt) {
        const int cur = kt & 1;
        if (kt < 15) stageKV(kt + 1, cur ^ 1);
        const int key0 = kt*64;
        const u16* Kc = Ks[cur];
        const u16* Vc = Vs[cur];

        float Sv[4][4];
        #pragma unroll
        for (int kb = 0; kb < 4; ++kb) {
            bf16x8 k0f = *(const bf16x8*)(Kc + (kb*16 + r16)*LD + g*8);
            bf16x8 k1f = *(const bf16x8*)(Kc + (kb*16 + r16)*LD + 32 + g*8);
            f32x4 S = z4;
            S = MFMA(aQ0, k0f, S);
            S = MFMA(aQ1, k1f, S);
            int keyg = key0 + kb*16 + r16;
            int kgh = keyg >> 5, kgw = keyg & 31;
            #pragma unroll
            for (int r = 0; r < 4; ++r) {
                int qg = qg_base + r;
                int rel = ((qg >> 5) - kgh + 31)*63 + ((qg & 31) - kgw + 31);
                Sv[kb][r] = S[r]*0.125f + bt[rel*H + head];
            }
        }
        float mx[4], al[4], ps[4];
        #pragma unroll
        for (int r = 0; r < 4; ++r)
            mx[r] = fmaxf(fmaxf(Sv[0][r], Sv[1][r]), fmaxf(Sv[2][r], Sv[3][r]));
        #pragma unroll
        for (int msk = 1; msk < 16; msk <<= 1)
            #pragma unroll
            for (int r = 0; r < 4; ++r) mx[r] = fmaxf(mx[r], __shfl_xor(mx[r], msk, 64));
        #pragma unroll
        for (int r = 0; r < 4; ++r) {
            float nm = fmaxf(m_[r], mx[r]);
            al[r] = __expf(m_[r] - nm);
            m_[r] = nm;
            ps[r] = 0.f;
        }
        #pragma unroll
        for (int kb = 0; kb < 4; ++kb)
            #pragma unroll
            for (int r = 0; r < 4; ++r) {
                float p = __expf(Sv[kb][r] - m_[r]);
                Sv[kb][r] = p;
                ps[r] += p;
            }
        #pragma unroll
        for (int msk = 1; msk < 16; msk <<= 1)
            #pragma unroll
            for (int r = 0; r < 4; ++r) ps[r] += __shfl_xor(ps[r], msk, 64);
        #pragma unroll
        for (int r = 0; r < 4; ++r) l_[r] = l_[r]*al[r] + ps[r];
        #pragma unroll
        for (int kb = 0; kb < 4; ++kb)
            #pragma unroll
            for (int r = 0; r < 4; ++r)
                Ps[wave][(g*4 + r)*LD + kb*16 + r16] = f2bf(Sv[kb][r]);
        #pragma unroll
        for (int dt = 0; dt < 4; ++dt)
            #pragma unroll
            for (int r = 0; r < 4; ++r) O[dt][r] = O[dt][r]*al[r];
        // Ps[wave] write->read is same-wave: compiler's lgkmcnt wait suffices, no barrier.
        bf16x8 aP0 = *(const bf16x8*)(Ps[wave] + r16*LD + g*8);
        bf16x8 aP1 = *(const bf16x8*)(Ps[wave] + r16*LD + 32 + g*8);
        #pragma unroll
        for (int dt = 0; dt < 4; ++dt) {
            bf16x8 v0 = *(const bf16x8*)(Vc + (dt*16 + r16)*LD + g*8);
            bf16x8 v1 = *(const bf16x8*)(Vc + (dt*16 + r16)*LD + 32 + g*8);
            O[dt] = MFMA(aP0, v0, O[dt]);
            O[dt] = MFMA(aP1, v1, O[dt]);
        }
        __syncthreads();   // buf^1 staged by all + cur reads done -> safe to swap
    }
    #pragma unroll
    for (int dt = 0; dt < 4; ++dt)
        #pragma unroll
        for (int r = 0; r < 4; ++r) {
            int token = q0 + wave*16 + g*4 + r;
            o[(tokbase + token)*inner + hoff + dt*16 + r16] = f2bf(O[dt][r] / l_[r]);
        }
}

// ---------------- final: x[b][n][d] -> out[b][d][gh][gw] ----------------
__global__ void k_out_transpose(const float* __restrict__ x, float* __restrict__ o)
{
    __shared__ float T[32*33];
    int d0 = blockIdx.x*32, n0 = blockIdx.y*32, b = blockIdx.z;
    int t = threadIdx.x, r = t >> 5, c = t & 31;
    #pragma unroll
    for (int i = 0; i < 4; ++i)
        T[(r+i*8)*33 + c] = x[((size_t)b*1024 + n0 + r + i*8)*512 + d0 + c];
    __syncthreads();
    #pragma unroll
    for (int i = 0; i < 4; ++i)
        o[((size_t)b*512 + d0 + r + i*8)*1024 + n0 + c] = T[c*33 + (r+i*8)];
}

extern "C" void kernel_launch(void* const* d_in, const int* in_sizes, int n_in,
                              void* d_out, int out_size, void* d_ws, size_t ws_size,
                              hipStream_t stream)
{
    (void)in_sizes; (void)n_in; (void)out_size; (void)ws_size;
    const float* img     = (const float*)d_in[0];
    const float* patch_w = (const float*)d_in[1];
    const float* patch_b = (const float*)d_in[2];
    const float* pos_emb = (const float*)d_in[3];
    const float* ln1_s   = (const float*)d_in[4];
    const float* ln1_b   = (const float*)d_in[5];
    const float* ln2_s   = (const float*)d_in[6];
    const float* ln2_b   = (const float*)d_in[7];
    const float* qkv_w[3] = {(const float*)d_in[8],  (const float*)d_in[12], (const float*)d_in[16]};
    const float* out_w[3] = {(const float*)d_in[9],  (const float*)d_in[13], (const float*)d_in[17]};
    const float* out_b[3] = {(const float*)d_in[10], (const float*)d_in[14], (const float*)d_in[18]};
    const float* biasT[3] = {(const float*)d_in[11], (const float*)d_in[15], (const float*)d_in[19]};
    const float* ff_w1 = (const float*)d_in[20];
    const float* ff_b1 = (const float*)d_in[21];
    const float* ff_w2 = (const float*)d_in[22];
    const float* ff_b2 = (const float*)d_in[23];
    float* out = (float*)d_out;

    const int HS[3] = {2,4,8};
    char* ws = (char*)d_ws;
    size_t off = 0;
    auto alloc = [&](size_t bytes) -> void* {
        void* p = ws + off; off += (bytes + 255) & ~(size_t)255; return p;
    };
    u16*   pwT  = (u16*)  alloc(512ull*32768*2);
    float* x    = (float*)alloc(4096ull*512*4);
    u16*   xn   = (u16*)  alloc(4096ull*512*2);
    u16*   qkv  = (u16*)  alloc(4096ull*1536*2);
    u16*   ob   = (u16*)  alloc(4096ull*512*2);
    u16*   mid  = (u16*)  alloc(4096ull*256*2);
    u16* qkvT[3]; u16* outT[3]; u16* f1T[3]; u16* f2T[3];
    for (int l = 0; l < 3; ++l) {
        int inner = 64*HS[l];
        qkvT[l] = (u16*)alloc((size_t)3*inner*512*2);
        outT[l] = (u16*)alloc((size_t)512*inner*2);
        f1T[l]  = (u16*)alloc((size_t)256*512*2);
        f2T[l]  = (u16*)alloc((size_t)512*256*2);
    }

    // ---- weight prep (once, up front) ----
    k_prep_pw<<<dim3(1024,16), 256, 0, stream>>>(patch_w, pwT);
    PrepArgs pa;
    for (int l = 0; l < 3; ++l) {
        int inner = 64*HS[l];
        pa.src[l]   = qkv_w[l];              pa.K[l]   = 512;   pa.N[l]   = 3*inner; pa.dst[l]   = qkvT[l];
        pa.src[3+l] = out_w[l];              pa.K[3+l] = inner; pa.N[3+l] = 512;     pa.dst[3+l] = outT[l];
        pa.src[6+l] = ff_w1 + (size_t)l*512*256; pa.K[6+l] = 512; pa.N[6+l] = 256;   pa.dst[6+l] = f1T[l];
        pa.src[9+l] = ff_w2 + (size_t)l*256*512; pa.K[9+l] = 256; pa.N[9+l] = 512;   pa.dst[9+l] = f2T[l];
    }
    k_prep_weights<<<dim3(16,48,12), 256, 0, stream>>>(pa);

    // ---- patch embed: x = patches(img) @ pwT^T + patch_b + pos_emb ----
    k_init_x<<<2048, 256, 0, stream>>>(x, patch_b, pos_emb);
    k_gemm_patch<<<1024, 256, 0, stream>>>(img, pwT, x);

    // ---- transformer layers ----
    for (int l = 0; l < 3; ++l) {
        int h = HS[l], inner = 64*h, n3 = 3*inner;
        k_ln<<<1024, 256, 0, stream>>>(x, ln1_s + l*512, ln1_b + l*512, xn);
        k_gemm64<1><<<dim3(64, n3/64), 256, 0, stream>>>(xn, 512, qkvT[l], 512, 512,
                                                         nullptr, qkv, n3, nullptr);
        k_attn<<<dim3(16, h, 4), 256, 0, stream>>>(qkv, biasT[l], ob, h);
        k_gemm64<3><<<dim3(64, 8), 256, 0, stream>>>(ob, inner, outT[l], inner, inner,
                                                     x, nullptr, 512, out_b[l]);
        k_ln<<<1024, 256, 0, stream>>>(x, ln2_s + l*512, ln2_b + l*512, xn);
        k_gemm64<2><<<dim3(64, 4), 256, 0, stream>>>(xn, 512, f1T[l], 512, 512,
                                                     nullptr, mid, 256, ff_b1 + l*256);
        k_gemm64<3><<<dim3(64, 8), 256, 0, stream>>>(mid, 256, f2T[l], 256, 256,
                                                     x, nullptr, 512, ff_b2 + l*512);
    }
    k_out_transpose<<<dim3(16, 32, 4), 256, 0, stream>>>(x, out);
}

// Round 8
// 1213.874 us; speedup vs baseline: 1.0861x; 1.0117x over previous
//
#include <hip/hip_runtime.h>

typedef unsigned short u16;
typedef __bf16 bf16x8 __attribute__((ext_vector_type(8)));
typedef float f32x4 __attribute__((ext_vector_type(4)));

#define AS1 __attribute__((address_space(1)))
#define AS3 __attribute__((address_space(3)))
#define MFMA(a,b,c) __builtin_amdgcn_mfma_f32_16x16x32_bf16(a,b,c,0,0,0)

__device__ __forceinline__ u16 f2bf(float f) {
    union { float f; unsigned u; } x; x.f = f;
    unsigned r = x.u + 0x7fffu + ((x.u >> 16) & 1u);
    return (u16)(r >> 16);
}

// ---------------- patch_w prep: pwT[n][k'] = w[k(k')][n] bf16, k' = c*256 + p1*16 + p2 ----------------
__global__ void k_prep_pw(const float* __restrict__ in, u16* __restrict__ o)
{
    __shared__ float T[32*33];
    int kp0 = blockIdx.x*32, n0 = blockIdx.y*32;
    int t = threadIdx.x, r = t >> 5, cc = t & 31;
    #pragma unroll
    for (int i = 0; i < 4; ++i) {
        int kp = kp0 + r + i*8;
        int korig = ((kp >> 4) & 15)*2048 + (kp & 15)*128 + (kp >> 8);
        T[(r + i*8)*33 + cc] = in[(size_t)korig*512 + n0 + cc];
    }
    __syncthreads();
    #pragma unroll
    for (int i = 0; i < 4; ++i)
        o[(size_t)(n0 + r + i*8)*32768 + kp0 + cc] = f2bf(T[cc*33 + r + i*8]);
}

// ---------------- all small weight transposes in ONE launch: out[N][K] = f2bf(in[K][N]^T) ----------------
struct PrepArgs {
    const float* src[12];
    u16* dst[12];
    int K[12];
    int N[12];
};
__global__ void k_prep_weights(PrepArgs a)
{
    __shared__ float T[32*33];
    int z = blockIdx.z;
    int K = a.K[z], N = a.N[z];
    int kt = blockIdx.x*32, nt = blockIdx.y*32;
    if (kt >= K || nt >= N) return;
    const float* in = a.src[z];
    u16* o = a.dst[z];
    int t = threadIdx.x, r = t >> 5, c = t & 31;
    #pragma unroll
    for (int i = 0; i < 4; ++i)
        T[(r + i*8)*33 + c] = in[(size_t)(kt + r + i*8)*N + nt + c];
    __syncthreads();
    #pragma unroll
    for (int i = 0; i < 4; ++i)
        o[(size_t)(nt + r + i*8)*K + kt + c] = f2bf(T[c*33 + r + i*8]);
}

// ---------------- x init: patch_b + pos_emb ----------------
__global__ void k_init_x(float* __restrict__ x, const float* __restrict__ pb, const float* __restrict__ pe)
{
    int i4 = blockIdx.x*256 + threadIdx.x;
    size_t base = (size_t)i4*4;
    float4 a = *(const float4*)(pb + (base & 511));
    float4 b = *(const float4*)(pe + (base & 524287));
    float4 r = make_float4(a.x+b.x, a.y+b.y, a.z+b.z, a.w+b.w);
    *(float4*)(x + base) = r;
}

// ---------------- implicit patch-embed GEMM: x += patches(img) @ pwT^T ----------------
// Pipelined, NO vmcnt-draining barriers in steady state:
//  per iter: cvt rA(k+1)->Af[nb]  (compiler's rA wait implicitly retires B(k) gload_lds),
//            issue B(k+1) gload_lds + A(k+2) reg loads (stay in flight across barrier),
//            MFMA on [cb], then lgkmcnt(0) + sched_barrier + RAW s_barrier.
// T2 swizzle on Bs retained (source chunk XOR + read XOR). K-order identical ->
// bit-identical accumulation vs rounds 3/7.
__global__ __launch_bounds__(256) void k_gemm_patch(
    const float* __restrict__ img, const u16* __restrict__ Bt,
    float* __restrict__ Cf)
{
    __shared__ alignas(16) u16 Af[2][16*512];
    __shared__ alignas(16) u16 Bs[2][128*64];
    const int t = threadIdx.x;
    const int bid = blockIdx.x;
    const int xcd = bid & 7, rr = bid >> 3;
    const int nt = rr & 3, q = rr >> 2;
    const int mz = q*8 + xcd;                 // [0,256) bijective
    const int mt = mz & 31, z = mz >> 5;
    const int m0 = mt*128, n0 = nt*128;
    const int b = m0 >> 10, gh0 = (m0 & 1023) >> 5;
    const int kz = z*4096;
    const int wave = t >> 6, lane = t & 63;
    const int r16 = lane & 15, g = lane >> 4;
    const int wmh = wave >> 1;
    const int wm = wmh*64, wn = (wave & 1)*64;

    const u16* Bb = Bt + (size_t)(n0 + (t>>3))*32768 + kz + (size_t)(((t&7) ^ ((t>>3)&7))*8);
    const int bsd = t*8;

    const float* imgB = img + (size_t)b*33554432 + (size_t)gh0*8192;
    int foff[4];
    #pragma unroll
    for (int i = 0; i < 4; ++i) {
        int F = i*4 + wave;
        int im_ = (F >> 1) & 3, ks = F & 1, wh = F >> 3;
        int mb = wh*64 + im_*16 + r16;
        int p1l = ks*2 + (g >> 1), p2b = (g & 1)*8;
        foff[i] = ((mb >> 5)*16 + p1l)*512 + (mb & 31)*16 + p2b;
    }

    f32x4 acc[4][4];
    const f32x4 z4 = {0.f,0.f,0.f,0.f};
    #pragma unroll
    for (int im_ = 0; im_ < 4; ++im_)
        #pragma unroll
        for (int in_ = 0; in_ < 4; ++in_) acc[im_][in_] = z4;

    float4 v0[4], v1[4];
    auto loadA = [&](int k) {
        const int koff = kz + k;
        const float* srcK = imgB + (size_t)(koff >> 8)*262144 + ((koff >> 4) & 15)*512;
        #pragma unroll
        for (int i = 0; i < 4; ++i) {
            const float* s = srcK + foff[i];
            v0[i] = *(const float4*)s;
            v1[i] = *(const float4*)(s + 4);
        }
    };
    auto cvtA = [&](int buf) {
        #pragma unroll
        for (int i = 0; i < 4; ++i) {
            bf16x8 pk;
            pk[0] = (__bf16)v0[i].x; pk[1] = (__bf16)v0[i].y; pk[2] = (__bf16)v0[i].z; pk[3] = (__bf16)v0[i].w;
            pk[4] = (__bf16)v1[i].x; pk[5] = (__bf16)v1[i].y; pk[6] = (__bf16)v1[i].z; pk[7] = (__bf16)v1[i].w;
            *(bf16x8*)(&Af[buf][(i*4 + wave)*512 + lane*8]) = pk;
        }
    };
    auto stageB = [&](int k, int buf) {
        #pragma unroll
        for (int i = 0; i < 4; ++i)
            __builtin_amdgcn_global_load_lds((AS1 void*)(Bb + (size_t)i*32*32768 + k),
                                             (AS3 void*)(&Bs[buf][bsd + i*2048]), 16, 0, 0);
    };

    // ---- prologue: A(0)->Af[0], B(0)+A(64) left in flight ----
    loadA(0);
    cvtA(0);                         // compiler waits rA here (nothing else pending)
    stageB(0, 0);                    // 4 vmem in flight
    loadA(64);                       // +8 in flight
    asm volatile("s_waitcnt lgkmcnt(0)" ::: "memory");
    __builtin_amdgcn_sched_barrier(0);
    __builtin_amdgcn_s_barrier();    // Af[0] visible
    __builtin_amdgcn_sched_barrier(0);

    for (int k = 0; k < 4096; k += 64) {
        const int cb = (k >> 6) & 1, nb = cb ^ 1;
        if (k + 64 < 4096) {
            cvtA(nb);                // rA=A(k+64) wait retires older B(k) gload_lds too
            stageB(k + 64, nb);      // in flight across this iter's MFMA + barrier
            if (k + 128 < 4096) loadA(k + 128);
        } else {
            asm volatile("s_waitcnt vmcnt(0)" ::: "memory");  // final tile: drain B(k)
            __builtin_amdgcn_sched_barrier(0);
        }
        #pragma unroll
        for (int kk = 0; kk < 64; kk += 32) {
            const int ks = kk >> 5;
            bf16x8 af[4], bfr[4];
            #pragma unroll
            for (int im_ = 0; im_ < 4; ++im_)
                af[im_] = *(const bf16x8*)(&Af[cb][(wmh*8 + im_*2 + ks)*512 + lane*8]);
            #pragma unroll
            for (int in_ = 0; in_ < 4; ++in_)
                bfr[in_] = *(const bf16x8*)(&Bs[cb][(wn + in_*16 + r16)*64 + ((ks*4 + g) ^ (r16 & 7))*8]);
            #pragma unroll
            for (int im_ = 0; im_ < 4; ++im_)
                #pragma unroll
                for (int in_ = 0; in_ < 4; ++in_)
                    acc[im_][in_] = MFMA(af[im_], bfr[in_], acc[im_][in_]);
        }
        asm volatile("s_waitcnt lgkmcnt(0)" ::: "memory");
        __builtin_amdgcn_sched_barrier(0);
        __builtin_amdgcn_s_barrier();    // no vmcnt drain: B(k+1)/A(k+2) stay in flight
        __builtin_amdgcn_sched_barrier(0);
    }
    #pragma unroll
    for (int im_ = 0; im_ < 4; ++im_) {
        int row = m0 + wm + im_*16 + g*4;
        #pragma unroll
        for (int in_ = 0; in_ < 4; ++in_) {
            int col = n0 + wn + in_*16 + r16;
            #pragma unroll
            for (int r4 = 0; r4 < 4; ++r4)
                __hip_atomic_fetch_add(&Cf[(size_t)(row + r4)*512 + col], acc[im_][in_][r4],
                                       __ATOMIC_RELAXED, __HIP_MEMORY_SCOPE_AGENT);
        }
    }
}

// ---------------- LayerNorm: 4 rows per 256-thread block (1 wave/row), fp32 in -> bf16 out ----------------
__global__ __launch_bounds__(256) void k_ln(const float* __restrict__ x, const float* __restrict__ sc,
                                            const float* __restrict__ bi, u16* __restrict__ o)
{
    int row = blockIdx.x*4 + (threadIdx.x >> 6), lane = threadIdx.x & 63;
    const float* xr = x + (size_t)row*512 + lane*8;
    float4 v0 = *(const float4*)xr;
    float4 v1 = *(const float4*)(xr + 4);
    float vv[8] = {v0.x,v0.y,v0.z,v0.w,v1.x,v1.y,v1.z,v1.w};
    float sum = 0.f, sq = 0.f;
    #pragma unroll
    for (int i = 0; i < 8; ++i) { sum += vv[i]; sq += vv[i]*vv[i]; }
    #pragma unroll
    for (int m = 1; m < 64; m <<= 1) { sum += __shfl_xor(sum, m, 64); sq += __shfl_xor(sq, m, 64); }
    float mean = sum * (1.f/512.f);
    float var  = sq  * (1.f/512.f) - mean*mean;
    float rstd = rsqrtf(var + 1e-5f);
    int d = lane*8;
    union { u16 u[8]; uint4 v; } pk;
    #pragma unroll
    for (int i = 0; i < 8; ++i) pk.u[i] = f2bf((vv[i]-mean)*rstd*sc[d+i] + bi[d+i]);
    *(uint4*)(o + (size_t)row*512 + d) = pk.v;
}

// ---------------- small-N bf16 GEMM: 64x64x64 tiles, 4 waves, 2x2 frags/wave ----------------
// T2 swizzle on BOTH As and Bs. EPI: 1 = bf16 store, 2 = gelu(acc+bias) bf16, 3 = Cf += acc+bias
template<int EPI>
__global__ __launch_bounds__(256) void k_gemm64(
    const u16* __restrict__ A, int lda,
    const u16* __restrict__ Bt, int ldb,
    int Kblk,
    float* __restrict__ Cf, u16* __restrict__ Cb, int ldc,
    const float* __restrict__ bias)
{
    __shared__ alignas(16) u16 As[64*64];
    __shared__ alignas(16) u16 Bs[64*64];
    const int t = threadIdx.x;
    const int m0 = blockIdx.x*64, n0 = blockIdx.y*64;
    const int wave = t >> 6, lane = t & 63;
    const int wm = (wave >> 1)*32, wn = (wave & 1)*32;
    const int r16 = lane & 15, g = lane >> 4;
    const int swz = ((t&7) ^ ((t>>3)&7))*8;
    const u16* Ab = A + (size_t)(m0 + (t>>3))*lda + swz;
    const u16* Bb = Bt + (size_t)(n0 + (t>>3))*ldb + swz;
    u16* Asd = As + t*8;
    u16* Bsd = Bs + t*8;
    f32x4 acc[2][2];
    const f32x4 z4 = {0.f,0.f,0.f,0.f};
    #pragma unroll
    for (int im = 0; im < 2; ++im)
        #pragma unroll
        for (int in_ = 0; in_ < 2; ++in_) acc[im][in_] = z4;

    for (int k = 0; k < Kblk; k += 64) {
        #pragma unroll
        for (int i = 0; i < 2; ++i) {
            __builtin_amdgcn_global_load_lds((AS1 void*)(Ab + (size_t)i*32*lda + k), (AS3 void*)(Asd + i*2048), 16, 0, 0);
            __builtin_amdgcn_global_load_lds((AS1 void*)(Bb + (size_t)i*32*ldb + k), (AS3 void*)(Bsd + i*2048), 16, 0, 0);
        }
        __syncthreads();
        #pragma unroll
        for (int kk = 0; kk < 64; kk += 32) {
            const int ks = kk >> 5;
            const int rchunk = ((ks*4 + g) ^ (r16 & 7))*8;
            bf16x8 af[2], bfr[2];
            #pragma unroll
            for (int im = 0; im < 2; ++im)
                af[im] = *(const bf16x8*)(As + (wm + im*16 + r16)*64 + rchunk);
            #pragma unroll
            for (int in_ = 0; in_ < 2; ++in_)
                bfr[in_] = *(const bf16x8*)(Bs + (wn + in_*16 + r16)*64 + rchunk);
            #pragma unroll
            for (int im = 0; im < 2; ++im)
                #pragma unroll
                for (int in_ = 0; in_ < 2; ++in_)
                    acc[im][in_] = MFMA(af[im], bfr[in_], acc[im][in_]);
        }
        __syncthreads();
    }
    #pragma unroll
    for (int im = 0; im < 2; ++im) {
        int row = m0 + wm + im*16 + g*4;
        #pragma unroll
        for (int in_ = 0; in_ < 2; ++in_) {
            int col = n0 + wn + in_*16 + r16;
            #pragma unroll
            for (int r = 0; r < 4; ++r) {
                float v = acc[im][in_][r];
                size_t idx = (size_t)(row + r)*ldc + col;
                if constexpr (EPI == 1) {
                    Cb[idx] = f2bf(v);
                } else if constexpr (EPI == 2) {
                    float xv = v + bias[col];
                    Cb[idx] = f2bf(0.5f*xv*(1.f + erff(xv*0.70710678118654752f)));
                } else {
                    Cf[idx] += v + bias[col];
                }
            }
        }
    }
}

// ---------------- flash attention with relative position bias ----------------
// K/V double-buffered in LDS, ONE barrier per kt-tile (stage kt+1 at loop top).
__global__ __launch_bounds__(256) void k_attn(
    const u16* __restrict__ qkv, const float* __restrict__ bt,
    u16* __restrict__ o, int H)
{
    const int LD = 80;
    __shared__ alignas(16) u16 Qs[64*80];
    __shared__ alignas(16) u16 Ks[2][64*80], Vs[2][64*80];
    __shared__ alignas(16) u16 Ps[4][16*80];
    const int inner = H*64, s3 = 3*inner;
    const int qt = blockIdx.x, head = blockIdx.y, b = blockIdx.z;
    const int t = threadIdx.x, wave = t >> 6, lane = t & 63;
    const int r16 = lane & 15, g = lane >> 4;
    const int q0 = qt*64;
    const size_t tokbase = (size_t)b*1024;
    const int hoff = head*64;

    #pragma unroll
    for (int it = 0; it < 2; ++it) {
        int flat = it*256 + t, r = flat >> 3, d0 = (flat & 7)*8;
        uint4 v = *(const uint4*)(qkv + (tokbase + q0 + r)*s3 + hoff + d0);
        *(uint4*)(Qs + r*LD + d0) = v;
    }

    auto stageKV = [&](int kt, int bufi) {
        const int key0 = kt*64;
        #pragma unroll
        for (int it = 0; it < 2; ++it) {
            int flat = it*256 + t, r = flat >> 3, d0 = (flat & 7)*8;
            uint4 v = *(const uint4*)(qkv + (tokbase + key0 + r)*s3 + inner + hoff + d0);
            *(uint4*)(Ks[bufi] + r*LD + d0) = v;
        }
        #pragma unroll
        for (int it = 0; it < 2; ++it) {
            int flat = it*256 + t, key = flat & 63, d0 = (flat >> 6)*8;
            uint4 v = *(const uint4*)(qkv + (tokbase + key0 + key)*s3 + 2*inner + hoff + d0);
            const u16* pv = (const u16*)&v;
            #pragma unroll
            for (int i = 0; i < 8; ++i) Vs[bufi][(d0+i)*LD + key] = pv[i];
        }
    };

    stageKV(0, 0);
    __syncthreads();

    bf16x8 aQ0 = *(const bf16x8*)(Qs + (wave*16 + r16)*LD + g*8);
    bf16x8 aQ1 = *(const bf16x8*)(Qs + (wave*16 + r16)*LD + 32 + g*8);

    float m_[4], l_[4];
    f32x4 O[4];
    const f32x4 z4 = {0.f,0.f,0.f,0.f};
    #pragma unroll
    for (int r = 0; r < 4; ++r) { m_[r] = -1e30f; l_[r] = 0.f; O[r] = z4; }
    const int qg_base = q0 + wave*16 + g*4;

    for (int kt = 0; kt < 16; ++kt) {
        const int cur = kt & 1;
        if (kt < 15) stageKV(kt + 1, cur ^ 1);
        const int key0 = kt*64;
        const u16* Kc = Ks[cur];
        const u16* Vc = Vs[cur];

        float Sv[4][4];
        #pragma unroll
        for (int kb = 0; kb < 4; ++kb) {
            bf16x8 k0f = *(const bf16x8*)(Kc + (kb*16 + r16)*LD + g*8);
            bf16x8 k1f = *(const bf16x8*)(Kc + (kb*16 + r16)*LD + 32 + g*8);
            f32x4 S = z4;
            S = MFMA(aQ0, k0f, S);
            S = MFMA(aQ1, k1f, S);
            int keyg = key0 + kb*16 + r16;
            int kgh = keyg >> 5, kgw = keyg & 31;
            #pragma unroll
            for (int r = 0; r < 4; ++r) {
                int qg = qg_base + r;
                int rel = ((qg >> 5) - kgh + 31)*63 + ((qg & 31) - kgw + 31);
                Sv[kb][r] = S[r]*0.125f + bt[rel*H + head];
            }
        }
        float mx[4], al[4], ps[4];
        #pragma unroll
        for (int r = 0; r < 4; ++r)
            mx[r] = fmaxf(fmaxf(Sv[0][r], Sv[1][r]), fmaxf(Sv[2][r], Sv[3][r]));
        #pragma unroll
        for (int msk = 1; msk < 16; msk <<= 1)
            #pragma unroll
            for (int r = 0; r < 4; ++r) mx[r] = fmaxf(mx[r], __shfl_xor(mx[r], msk, 64));
        #pragma unroll
        for (int r = 0; r < 4; ++r) {
            float nm = fmaxf(m_[r], mx[r]);
            al[r] = __expf(m_[r] - nm);
            m_[r] = nm;
            ps[r] = 0.f;
        }
        #pragma unroll
        for (int kb = 0; kb < 4; ++kb)
            #pragma unroll
            for (int r = 0; r < 4; ++r) {
                float p = __expf(Sv[kb][r] - m_[r]);
                Sv[kb][r] = p;
                ps[r] += p;
            }
        #pragma unroll
        for (int msk = 1; msk < 16; msk <<= 1)
            #pragma unroll
            for (int r = 0; r < 4; ++r) ps[r] += __shfl_xor(ps[r], msk, 64);
        #pragma unroll
        for (int r = 0; r < 4; ++r) l_[r] = l_[r]*al[r] + ps[r];
        #pragma unroll
        for (int kb = 0; kb < 4; ++kb)
            #pragma unroll
            for (int r = 0; r < 4; ++r)
                Ps[wave][(g*4 + r)*LD + kb*16 + r16] = f2bf(Sv[kb][r]);
        #pragma unroll
        for (int dt = 0; dt < 4; ++dt)
            #pragma unroll
            for (int r = 0; r < 4; ++r) O[dt][r] = O[dt][r]*al[r];
        // Ps[wave] write->read is same-wave: compiler's lgkmcnt wait suffices, no barrier.
        bf16x8 aP0 = *(const bf16x8*)(Ps[wave] + r16*LD + g*8);
        bf16x8 aP1 = *(const bf16x8*)(Ps[wave] + r16*LD + 32 + g*8);
        #pragma unroll
        for (int dt = 0; dt < 4; ++dt) {
            bf16x8 v0 = *(const bf16x8*)(Vc + (dt*16 + r16)*LD + g*8);
            bf16x8 v1 = *(const bf16x8*)(Vc + (dt*16 + r16)*LD + 32 + g*8);
            O[dt] = MFMA(aP0, v0, O[dt]);
            O[dt] = MFMA(aP1, v1, O[dt]);
        }
        __syncthreads();   // buf^1 staged by all + cur reads done -> safe to swap
    }
    #pragma unroll
    for (int dt = 0; dt < 4; ++dt)
        #pragma unroll
        for (int r = 0; r < 4; ++r) {
            int token = q0 + wave*16 + g*4 + r;
            o[(tokbase + token)*inner + hoff + dt*16 + r16] = f2bf(O[dt][r] / l_[r]);
        }
}

// ---------------- final: x[b][n][d] -> out[b][d][gh][gw] ----------------
__global__ void k_out_transpose(const float* __restrict__ x, float* __restrict__ o)
{
    __shared__ float T[32*33];
    int d0 = blockIdx.x*32, n0 = blockIdx.y*32, b = blockIdx.z;
    int t = threadIdx.x, r = t >> 5, c = t & 31;
    #pragma unroll
    for (int i = 0; i < 4; ++i)
        T[(r+i*8)*33 + c] = x[((size_t)b*1024 + n0 + r + i*8)*512 + d0 + c];
    __syncthreads();
    #pragma unroll
    for (int i = 0; i < 4; ++i)
        o[((size_t)b*512 + d0 + r + i*8)*1024 + n0 + c] = T[c*33 + (r+i*8)];
}

extern "C" void kernel_launch(void* const* d_in, const int* in_sizes, int n_in,
                              void* d_out, int out_size, void* d_ws, size_t ws_size,
                              hipStream_t stream)
{
    (void)in_sizes; (void)n_in; (void)out_size; (void)ws_size;
    const float* img     = (const float*)d_in[0];
    const float* patch_w = (const float*)d_in[1];
    const float* patch_b = (const float*)d_in[2];
    const float* pos_emb = (const float*)d_in[3];
    const float* ln1_s   = (const float*)d_in[4];
    const float* ln1_b   = (const float*)d_in[5];
    const float* ln2_s   = (const float*)d_in[6];
    const float* ln2_b   = (const float*)d_in[7];
    const float* qkv_w[3] = {(const float*)d_in[8],  (const float*)d_in[12], (const float*)d_in[16]};
    const float* out_w[3] = {(const float*)d_in[9],  (const float*)d_in[13], (const float*)d_in[17]};
    const float* out_b[3] = {(const float*)d_in[10], (const float*)d_in[14], (const float*)d_in[18]};
    const float* biasT[3] = {(const float*)d_in[11], (const float*)d_in[15], (const float*)d_in[19]};
    const float* ff_w1 = (const float*)d_in[20];
    const float* ff_b1 = (const float*)d_in[21];
    const float* ff_w2 = (const float*)d_in[22];
    const float* ff_b2 = (const float*)d_in[23];
    float* out = (float*)d_out;

    const int HS[3] = {2,4,8};
    char* ws = (char*)d_ws;
    size_t off = 0;
    auto alloc = [&](size_t bytes) -> void* {
        void* p = ws + off; off += (bytes + 255) & ~(size_t)255; return p;
    };
    u16*   pwT  = (u16*)  alloc(512ull*32768*2);
    float* x    = (float*)alloc(4096ull*512*4);
    u16*   xn   = (u16*)  alloc(4096ull*512*2);
    u16*   qkv  = (u16*)  alloc(4096ull*1536*2);
    u16*   ob   = (u16*)  alloc(4096ull*512*2);
    u16*   mid  = (u16*)  alloc(4096ull*256*2);
    u16* qkvT[3]; u16* outT[3]; u16* f1T[3]; u16* f2T[3];
    for (int l = 0; l < 3; ++l) {
        int inner = 64*HS[l];
        qkvT[l] = (u16*)alloc((size_t)3*inner*512*2);
        outT[l] = (u16*)alloc((size_t)512*inner*2);
        f1T[l]  = (u16*)alloc((size_t)256*512*2);
        f2T[l]  = (u16*)alloc((size_t)512*256*2);
    }

    // ---- weight prep (once, up front) ----
    k_prep_pw<<<dim3(1024,16), 256, 0, stream>>>(patch_w, pwT);
    PrepArgs pa;
    for (int l = 0; l < 3; ++l) {
        int inner = 64*HS[l];
        pa.src[l]   = qkv_w[l];              pa.K[l]   = 512;   pa.N[l]   = 3*inner; pa.dst[l]   = qkvT[l];
        pa.src[3+l] = out_w[l];              pa.K[3+l] = inner; pa.N[3+l] = 512;     pa.dst[3+l] = outT[l];
        pa.src[6+l] = ff_w1 + (size_t)l*512*256; pa.K[6+l] = 512; pa.N[6+l] = 256;   pa.dst[6+l] = f1T[l];
        pa.src[9+l] = ff_w2 + (size_t)l*256*512; pa.K[9+l] = 256; pa.N[9+l] = 512;   pa.dst[9+l] = f2T[l];
    }
    k_prep_weights<<<dim3(16,48,12), 256, 0, stream>>>(pa);

    // ---- patch embed: x = patches(img) @ pwT^T + patch_b + pos_emb ----
    k_init_x<<<2048, 256, 0, stream>>>(x, patch_b, pos_emb);
    k_gemm_patch<<<1024, 256, 0, stream>>>(img, pwT, x);

    // ---- transformer layers ----
    for (int l = 0; l < 3; ++l) {
        int h = HS[l], inner = 64*h, n3 = 3*inner;
        k_ln<<<1024, 256, 0, stream>>>(x, ln1_s + l*512, ln1_b + l*512, xn);
        k_gemm64<1><<<dim3(64, n3/64), 256, 0, stream>>>(xn, 512, qkvT[l], 512, 512,
                                                         nullptr, qkv, n3, nullptr);
        k_attn<<<dim3(16, h, 4), 256, 0, stream>>>(qkv, biasT[l], ob, h);
        k_gemm64<3><<<dim3(64, 8), 256, 0, stream>>>(ob, inner, outT[l], inner, inner,
                                                     x, nullptr, 512, out_b[l]);
        k_ln<<<1024, 256, 0, stream>>>(x, ln2_s + l*512, ln2_b + l*512, xn);
        k_gemm64<2><<<dim3(64, 4), 256, 0, stream>>>(xn, 512, f1T[l], 512, 512,
                                                     nullptr, mid, 256, ff_b1 + l*256);
        k_gemm64<3><<<dim3(64, 8), 256, 0, stream>>>(mid, 256, f2T[l], 256, 256,
                                                     x, nullptr, 512, ff_b2 + l*512);
    }
    k_out_transpose<<<dim3(16, 32, 4), 256, 0, stream>>>(x, out);
}

// Round 9
// 1197.793 us; speedup vs baseline: 1.1007x; 1.0134x over previous
//
#include <hip/hip_runtime.h>

typedef unsigned short u16;
typedef __bf16 bf16x8 __attribute__((ext_vector_type(8)));
typedef float f32x4 __attribute__((ext_vector_type(4)));

#define AS1 __attribute__((address_space(1)))
#define AS3 __attribute__((address_space(3)))
#define MFMA(a,b,c) __builtin_amdgcn_mfma_f32_16x16x32_bf16(a,b,c,0,0,0)

__device__ __forceinline__ u16 f2bf(float f) {
    union { float f; unsigned u; } x; x.f = f;
    unsigned r = x.u + 0x7fffu + ((x.u >> 16) & 1u);
    return (u16)(r >> 16);
}

// ---------------- patch_w prep: pwT[n][k'] = w[k(k')][n] bf16, k' = c*256 + p1*16 + p2 ----------------
__global__ void k_prep_pw(const float* __restrict__ in, u16* __restrict__ o)
{
    __shared__ float T[32*33];
    int kp0 = blockIdx.x*32, n0 = blockIdx.y*32;
    int t = threadIdx.x, r = t >> 5, cc = t & 31;
    #pragma unroll
    for (int i = 0; i < 4; ++i) {
        int kp = kp0 + r + i*8;
        int korig = ((kp >> 4) & 15)*2048 + (kp & 15)*128 + (kp >> 8);
        T[(r + i*8)*33 + cc] = in[(size_t)korig*512 + n0 + cc];
    }
    __syncthreads();
    #pragma unroll
    for (int i = 0; i < 4; ++i)
        o[(size_t)(n0 + r + i*8)*32768 + kp0 + cc] = f2bf(T[cc*33 + r + i*8]);
}

// ---------------- all small weight transposes in ONE launch: out[N][K] = f2bf(in[K][N]^T) ----------------
struct PrepArgs {
    const float* src[12];
    u16* dst[12];
    int K[12];
    int N[12];
};
__global__ void k_prep_weights(PrepArgs a)
{
    __shared__ float T[32*33];
    int z = blockIdx.z;
    int K = a.K[z], N = a.N[z];
    int kt = blockIdx.x*32, nt = blockIdx.y*32;
    if (kt >= K || nt >= N) return;
    const float* in = a.src[z];
    u16* o = a.dst[z];
    int t = threadIdx.x, r = t >> 5, c = t & 31;
    #pragma unroll
    for (int i = 0; i < 4; ++i)
        T[(r + i*8)*33 + c] = in[(size_t)(kt + r + i*8)*N + nt + c];
    __syncthreads();
    #pragma unroll
    for (int i = 0; i < 4; ++i)
        o[(size_t)(nt + r + i*8)*K + kt + c] = f2bf(T[c*33 + r + i*8]);
}

// ---------------- implicit patch-embed GEMM: part[z] = patches(img) @ pwT^T (K-slice z) ----------------
// Corrected counted-vmcnt pipeline (wait-BEFORE-barrier, T4):
//   per iter: cvtA(regs from last iter) -> Af[nb]; issue stageB(k+64) FIRST (oldest
//   in FIFO) then loadA(k+128); MFMA on [cb]; s_waitcnt vmcnt(8) retires exactly the
//   B gload_lds (cross-wave guarantee via the following barrier) while A's 8 loads
//   stay in flight; lgkmcnt(0); s_barrier. Tail iters use vmcnt(0).
// Epilogue: plain stores to per-z slab (no atomics); k_reduce_x sums slabs.
// T2 swizzle on Bs retained. K-order identical -> bit-identical per-z accumulation.
__global__ __launch_bounds__(256) void k_gemm_patch(
    const float* __restrict__ img, const u16* __restrict__ Bt,
    float* __restrict__ part)
{
    __shared__ alignas(16) u16 Af[2][16*512];
    __shared__ alignas(16) u16 Bs[2][128*64];
    const int t = threadIdx.x;
    const int bid = blockIdx.x;
    const int xcd = bid & 7, rr = bid >> 3;
    const int nt = rr & 3, q = rr >> 2;
    const int mz = q*8 + xcd;                 // [0,256) bijective
    const int mt = mz & 31, z = mz >> 5;
    const int m0 = mt*128, n0 = nt*128;
    const int b = m0 >> 10, gh0 = (m0 & 1023) >> 5;
    const int kz = z*4096;
    const int wave = t >> 6, lane = t & 63;
    const int r16 = lane & 15, g = lane >> 4;
    const int wmh = wave >> 1;
    const int wm = wmh*64, wn = (wave & 1)*64;

    const u16* Bb = Bt + (size_t)(n0 + (t>>3))*32768 + kz + (size_t)(((t&7) ^ ((t>>3)&7))*8);
    const int bsd = t*8;

    const float* imgB = img + (size_t)b*33554432 + (size_t)gh0*8192;
    int foff[4];
    #pragma unroll
    for (int i = 0; i < 4; ++i) {
        int F = i*4 + wave;
        int im_ = (F >> 1) & 3, ks = F & 1, wh = F >> 3;
        int mb = wh*64 + im_*16 + r16;
        int p1l = ks*2 + (g >> 1), p2b = (g & 1)*8;
        foff[i] = ((mb >> 5)*16 + p1l)*512 + (mb & 31)*16 + p2b;
    }

    f32x4 acc[4][4];
    const f32x4 z4 = {0.f,0.f,0.f,0.f};
    #pragma unroll
    for (int im_ = 0; im_ < 4; ++im_)
        #pragma unroll
        for (int in_ = 0; in_ < 4; ++in_) acc[im_][in_] = z4;

    float4 v0[4], v1[4];
    auto loadA = [&](int k) {
        const int koff = kz + k;
        const float* srcK = imgB + (size_t)(koff >> 8)*262144 + ((koff >> 4) & 15)*512;
        #pragma unroll
        for (int i = 0; i < 4; ++i) {
            const float* s = srcK + foff[i];
            v0[i] = *(const float4*)s;
            v1[i] = *(const float4*)(s + 4);
        }
    };
    auto cvtA = [&](int buf) {
        #pragma unroll
        for (int i = 0; i < 4; ++i) {
            bf16x8 pk;
            pk[0] = (__bf16)v0[i].x; pk[1] = (__bf16)v0[i].y; pk[2] = (__bf16)v0[i].z; pk[3] = (__bf16)v0[i].w;
            pk[4] = (__bf16)v1[i].x; pk[5] = (__bf16)v1[i].y; pk[6] = (__bf16)v1[i].z; pk[7] = (__bf16)v1[i].w;
            *(bf16x8*)(&Af[buf][(i*4 + wave)*512 + lane*8]) = pk;
        }
    };
    auto stageB = [&](int k, int buf) {
        #pragma unroll
        for (int i = 0; i < 4; ++i)
            __builtin_amdgcn_global_load_lds((AS1 void*)(Bb + (size_t)i*32*32768 + k),
                                             (AS3 void*)(&Bs[buf][bsd + i*2048]), 16, 0, 0);
    };

    // ---- prologue ----
    loadA(0);
    cvtA(0);                         // waits own A(0) loads (nothing else pending)
    stageB(0, 0);                    // B first in FIFO
    loadA(64);                       // A in flight across barrier
    asm volatile("s_waitcnt vmcnt(8)" ::: "memory");   // retire B(0) before barrier
    __builtin_amdgcn_sched_barrier(0);
    asm volatile("s_waitcnt lgkmcnt(0)" ::: "memory");
    __builtin_amdgcn_sched_barrier(0);
    __builtin_amdgcn_s_barrier();    // Af[0]+Bs[0] visible to all waves
    __builtin_amdgcn_sched_barrier(0);

    for (int k = 0; k < 4096; k += 64) {
        const int cb = (k >> 6) & 1, nb = cb ^ 1;
        const bool pre  = (k + 64  < 4096);
        const bool pre2 = (k + 128 < 4096);
        if (pre) {
            cvtA(nb);                // regs loaded last iter: wait is near-free
            stageB(k + 64, nb);      // B FIRST (oldest in FIFO)
            if (pre2) loadA(k + 128);
        }
        #pragma unroll
        for (int kk = 0; kk < 64; kk += 32) {
            const int ks = kk >> 5;
            bf16x8 af[4], bfr[4];
            #pragma unroll
            for (int im_ = 0; im_ < 4; ++im_)
                af[im_] = *(const bf16x8*)(&Af[cb][(wmh*8 + im_*2 + ks)*512 + lane*8]);
            #pragma unroll
            for (int in_ = 0; in_ < 4; ++in_)
                bfr[in_] = *(const bf16x8*)(&Bs[cb][(wn + in_*16 + r16)*64 + ((ks*4 + g) ^ (r16 & 7))*8]);
            #pragma unroll
            for (int im_ = 0; im_ < 4; ++im_)
                #pragma unroll
                for (int in_ = 0; in_ < 4; ++in_)
                    acc[im_][in_] = MFMA(af[im_], bfr[in_], acc[im_][in_]);
        }
        if (pre) {
            if (pre2) { asm volatile("s_waitcnt vmcnt(8)" ::: "memory"); }  // retire B(k+64), keep A(k+128)
            else      { asm volatile("s_waitcnt vmcnt(0)" ::: "memory"); }  // tail: drain
            __builtin_amdgcn_sched_barrier(0);
        }
        asm volatile("s_waitcnt lgkmcnt(0)" ::: "memory");
        __builtin_amdgcn_sched_barrier(0);
        __builtin_amdgcn_s_barrier();
        __builtin_amdgcn_sched_barrier(0);
    }
    float* slab = part + (size_t)z*2097152;
    #pragma unroll
    for (int im_ = 0; im_ < 4; ++im_) {
        int row = m0 + wm + im_*16 + g*4;
        #pragma unroll
        for (int in_ = 0; in_ < 4; ++in_) {
            int col = n0 + wn + in_*16 + r16;
            #pragma unroll
            for (int r4 = 0; r4 < 4; ++r4)
                slab[(size_t)(row + r4)*512 + col] = acc[im_][in_][r4];
        }
    }
}

// ---------------- reduce: x = patch_b + pos_emb + sum_z part[z] ----------------
__global__ void k_reduce_x(const float* __restrict__ part, const float* __restrict__ pb,
                           const float* __restrict__ pe, float* __restrict__ x)
{
    size_t base = ((size_t)blockIdx.x*256 + threadIdx.x)*4;
    float4 s = *(const float4*)(pb + (base & 511));
    float4 e = *(const float4*)(pe + (base & 524287));
    s.x += e.x; s.y += e.y; s.z += e.z; s.w += e.w;
    #pragma unroll
    for (int z = 0; z < 8; ++z) {
        float4 p = *(const float4*)(part + (size_t)z*2097152 + base);
        s.x += p.x; s.y += p.y; s.z += p.z; s.w += p.w;
    }
    *(float4*)(x + base) = s;
}

// ---------------- LayerNorm: 4 rows per 256-thread block (1 wave/row), fp32 in -> bf16 out ----------------
__global__ __launch_bounds__(256) void k_ln(const float* __restrict__ x, const float* __restrict__ sc,
                                            const float* __restrict__ bi, u16* __restrict__ o)
{
    int row = blockIdx.x*4 + (threadIdx.x >> 6), lane = threadIdx.x & 63;
    const float* xr = x + (size_t)row*512 + lane*8;
    float4 v0 = *(const float4*)xr;
    float4 v1 = *(const float4*)(xr + 4);
    float vv[8] = {v0.x,v0.y,v0.z,v0.w,v1.x,v1.y,v1.z,v1.w};
    float sum = 0.f, sq = 0.f;
    #pragma unroll
    for (int i = 0; i < 8; ++i) { sum += vv[i]; sq += vv[i]*vv[i]; }
    #pragma unroll
    for (int m = 1; m < 64; m <<= 1) { sum += __shfl_xor(sum, m, 64); sq += __shfl_xor(sq, m, 64); }
    float mean = sum * (1.f/512.f);
    float var  = sq  * (1.f/512.f) - mean*mean;
    float rstd = rsqrtf(var + 1e-5f);
    int d = lane*8;
    union { u16 u[8]; uint4 v; } pk;
    #pragma unroll
    for (int i = 0; i < 8; ++i) pk.u[i] = f2bf((vv[i]-mean)*rstd*sc[d+i] + bi[d+i]);
    *(uint4*)(o + (size_t)row*512 + d) = pk.v;
}

// ---------------- small-N bf16 GEMM: 64x64x64 tiles, 4 waves, 2x2 frags/wave ----------------
// T2 swizzle on BOTH As and Bs. EPI: 1 = bf16 store, 2 = gelu(acc+bias) bf16, 3 = Cf += acc+bias
template<int EPI>
__global__ __launch_bounds__(256) void k_gemm64(
    const u16* __restrict__ A, int lda,
    const u16* __restrict__ Bt, int ldb,
    int Kblk,
    float* __restrict__ Cf, u16* __restrict__ Cb, int ldc,
    const float* __restrict__ bias)
{
    __shared__ alignas(16) u16 As[64*64];
    __shared__ alignas(16) u16 Bs[64*64];
    const int t = threadIdx.x;
    const int m0 = blockIdx.x*64, n0 = blockIdx.y*64;
    const int wave = t >> 6, lane = t & 63;
    const int wm = (wave >> 1)*32, wn = (wave & 1)*32;
    const int r16 = lane & 15, g = lane >> 4;
    const int swz = ((t&7) ^ ((t>>3)&7))*8;
    const u16* Ab = A + (size_t)(m0 + (t>>3))*lda + swz;
    const u16* Bb = Bt + (size_t)(n0 + (t>>3))*ldb + swz;
    u16* Asd = As + t*8;
    u16* Bsd = Bs + t*8;
    f32x4 acc[2][2];
    const f32x4 z4 = {0.f,0.f,0.f,0.f};
    #pragma unroll
    for (int im = 0; im < 2; ++im)
        #pragma unroll
        for (int in_ = 0; in_ < 2; ++in_) acc[im][in_] = z4;

    for (int k = 0; k < Kblk; k += 64) {
        #pragma unroll
        for (int i = 0; i < 2; ++i) {
            __builtin_amdgcn_global_load_lds((AS1 void*)(Ab + (size_t)i*32*lda + k), (AS3 void*)(Asd + i*2048), 16, 0, 0);
            __builtin_amdgcn_global_load_lds((AS1 void*)(Bb + (size_t)i*32*ldb + k), (AS3 void*)(Bsd + i*2048), 16, 0, 0);
        }
        __syncthreads();
        #pragma unroll
        for (int kk = 0; kk < 64; kk += 32) {
            const int ks = kk >> 5;
            const int rchunk = ((ks*4 + g) ^ (r16 & 7))*8;
            bf16x8 af[2], bfr[2];
            #pragma unroll
            for (int im = 0; im < 2; ++im)
                af[im] = *(const bf16x8*)(As + (wm + im*16 + r16)*64 + rchunk);
            #pragma unroll
            for (int in_ = 0; in_ < 2; ++in_)
                bfr[in_] = *(const bf16x8*)(Bs + (wn + in_*16 + r16)*64 + rchunk);
            #pragma unroll
            for (int im = 0; im < 2; ++im)
                #pragma unroll
                for (int in_ = 0; in_ < 2; ++in_)
                    acc[im][in_] = MFMA(af[im], bfr[in_], acc[im][in_]);
        }
        __syncthreads();
    }
    #pragma unroll
    for (int im = 0; im < 2; ++im) {
        int row = m0 + wm + im*16 + g*4;
        #pragma unroll
        for (int in_ = 0; in_ < 2; ++in_) {
            int col = n0 + wn + in_*16 + r16;
            #pragma unroll
            for (int r = 0; r < 4; ++r) {
                float v = acc[im][in_][r];
                size_t idx = (size_t)(row + r)*ldc + col;
                if constexpr (EPI == 1) {
                    Cb[idx] = f2bf(v);
                } else if constexpr (EPI == 2) {
                    float xv = v + bias[col];
                    Cb[idx] = f2bf(0.5f*xv*(1.f + erff(xv*0.70710678118654752f)));
                } else {
                    Cf[idx] += v + bias[col];
                }
            }
        }
    }
}

// ---------------- flash attention with relative position bias ----------------
// K/V double-buffered in LDS, ONE barrier per kt-tile (stage kt+1 at loop top).
__global__ __launch_bounds__(256) void k_attn(
    const u16* __restrict__ qkv, const float* __restrict__ bt,
    u16* __restrict__ o, int H)
{
    const int LD = 80;
    __shared__ alignas(16) u16 Qs[64*80];
    __shared__ alignas(16) u16 Ks[2][64*80], Vs[2][64*80];
    __shared__ alignas(16) u16 Ps[4][16*80];
    const int inner = H*64, s3 = 3*inner;
    const int qt = blockIdx.x, head = blockIdx.y, b = blockIdx.z;
    const int t = threadIdx.x, wave = t >> 6, lane = t & 63;
    const int r16 = lane & 15, g = lane >> 4;
    const int q0 = qt*64;
    const size_t tokbase = (size_t)b*1024;
    const int hoff = head*64;

    #pragma unroll
    for (int it = 0; it < 2; ++it) {
        int flat = it*256 + t, r = flat >> 3, d0 = (flat & 7)*8;
        uint4 v = *(const uint4*)(qkv + (tokbase + q0 + r)*s3 + hoff + d0);
        *(uint4*)(Qs + r*LD + d0) = v;
    }

    auto stageKV = [&](int kt, int bufi) {
        const int key0 = kt*64;
        #pragma unroll
        for (int it = 0; it < 2; ++it) {
            int flat = it*256 + t, r = flat >> 3, d0 = (flat & 7)*8;
            uint4 v = *(const uint4*)(qkv + (tokbase + key0 + r)*s3 + inner + hoff + d0);
            *(uint4*)(Ks[bufi] + r*LD + d0) = v;
        }
        #pragma unroll
        for (int it = 0; it < 2; ++it) {
            int flat = it*256 + t, key = flat & 63, d0 = (flat >> 6)*8;
            uint4 v = *(const uint4*)(qkv + (tokbase + key0 + key)*s3 + 2*inner + hoff + d0);
            const u16* pv = (const u16*)&v;
            #pragma unroll
            for (int i = 0; i < 8; ++i) Vs[bufi][(d0+i)*LD + key] = pv[i];
        }
    };

    stageKV(0, 0);
    __syncthreads();

    bf16x8 aQ0 = *(const bf16x8*)(Qs + (wave*16 + r16)*LD + g*8);
    bf16x8 aQ1 = *(const bf16x8*)(Qs + (wave*16 + r16)*LD + 32 + g*8);

    float m_[4], l_[4];
    f32x4 O[4];
    const f32x4 z4 = {0.f,0.f,0.f,0.f};
    #pragma unroll
    for (int r = 0; r < 4; ++r) { m_[r] = -1e30f; l_[r] = 0.f; O[r] = z4; }
    const int qg_base = q0 + wave*16 + g*4;

    for (int kt = 0; kt < 16; ++kt) {
        const int cur = kt & 1;
        if (kt < 15) stageKV(kt + 1, cur ^ 1);
        const int key0 = kt*64;
        const u16* Kc = Ks[cur];
        const u16* Vc = Vs[cur];

        float Sv[4][4];
        #pragma unroll
        for (int kb = 0; kb < 4; ++kb) {
            bf16x8 k0f = *(const bf16x8*)(Kc + (kb*16 + r16)*LD + g*8);
            bf16x8 k1f = *(const bf16x8*)(Kc + (kb*16 + r16)*LD + 32 + g*8);
            f32x4 S = z4;
            S = MFMA(aQ0, k0f, S);
            S = MFMA(aQ1, k1f, S);
            int keyg = key0 + kb*16 + r16;
            int kgh = keyg >> 5, kgw = keyg & 31;
            #pragma unroll
            for (int r = 0; r < 4; ++r) {
                int qg = qg_base + r;
                int rel = ((qg >> 5) - kgh + 31)*63 + ((qg & 31) - kgw + 31);
                Sv[kb][r] = S[r]*0.125f + bt[rel*H + head];
            }
        }
        float mx[4], al[4], ps[4];
        #pragma unroll
        for (int r = 0; r < 4; ++r)
            mx[r] = fmaxf(fmaxf(Sv[0][r], Sv[1][r]), fmaxf(Sv[2][r], Sv[3][r]));
        #pragma unroll
        for (int msk = 1; msk < 16; msk <<= 1)
            #pragma unroll
            for (int r = 0; r < 4; ++r) mx[r] = fmaxf(mx[r], __shfl_xor(mx[r], msk, 64));
        #pragma unroll
        for (int r = 0; r < 4; ++r) {
            float nm = fmaxf(m_[r], mx[r]);
            al[r] = __expf(m_[r] - nm);
            m_[r] = nm;
            ps[r] = 0.f;
        }
        #pragma unroll
        for (int kb = 0; kb < 4; ++kb)
            #pragma unroll
            for (int r = 0; r < 4; ++r) {
                float p = __expf(Sv[kb][r] - m_[r]);
                Sv[kb][r] = p;
                ps[r] += p;
            }
        #pragma unroll
        for (int msk = 1; msk < 16; msk <<= 1)
            #pragma unroll
            for (int r = 0; r < 4; ++r) ps[r] += __shfl_xor(ps[r], msk, 64);
        #pragma unroll
        for (int r = 0; r < 4; ++r) l_[r] = l_[r]*al[r] + ps[r];
        #pragma unroll
        for (int kb = 0; kb < 4; ++kb)
            #pragma unroll
            for (int r = 0; r < 4; ++r)
                Ps[wave][(g*4 + r)*LD + kb*16 + r16] = f2bf(Sv[kb][r]);
        #pragma unroll
        for (int dt = 0; dt < 4; ++dt)
            #pragma unroll
            for (int r = 0; r < 4; ++r) O[dt][r] = O[dt][r]*al[r];
        // Ps[wave] write->read is same-wave: compiler's lgkmcnt wait suffices, no barrier.
        bf16x8 aP0 = *(const bf16x8*)(Ps[wave] + r16*LD + g*8);
        bf16x8 aP1 = *(const bf16x8*)(Ps[wave] + r16*LD + 32 + g*8);
        #pragma unroll
        for (int dt = 0; dt < 4; ++dt) {
            bf16x8 v0 = *(const bf16x8*)(Vc + (dt*16 + r16)*LD + g*8);
            bf16x8 v1 = *(const bf16x8*)(Vc + (dt*16 + r16)*LD + 32 + g*8);
            O[dt] = MFMA(aP0, v0, O[dt]);
            O[dt] = MFMA(aP1, v1, O[dt]);
        }
        __syncthreads();   // buf^1 staged by all + cur reads done -> safe to swap
    }
    #pragma unroll
    for (int dt = 0; dt < 4; ++dt)
        #pragma unroll
        for (int r = 0; r < 4; ++r) {
            int token = q0 + wave*16 + g*4 + r;
            o[(tokbase + token)*inner + hoff + dt*16 + r16] = f2bf(O[dt][r] / l_[r]);
        }
}

// ---------------- final: x[b][n][d] -> out[b][d][gh][gw] ----------------
__global__ void k_out_transpose(const float* __restrict__ x, float* __restrict__ o)
{
    __shared__ float T[32*33];
    int d0 = blockIdx.x*32, n0 = blockIdx.y*32, b = blockIdx.z;
    int t = threadIdx.x, r = t >> 5, c = t & 31;
    #pragma unroll
    for (int i = 0; i < 4; ++i)
        T[(r+i*8)*33 + c] = x[((size_t)b*1024 + n0 + r + i*8)*512 + d0 + c];
    __syncthreads();
    #pragma unroll
    for (int i = 0; i < 4; ++i)
        o[((size_t)b*512 + d0 + r + i*8)*1024 + n0 + c] = T[c*33 + (r+i*8)];
}

extern "C" void kernel_launch(void* const* d_in, const int* in_sizes, int n_in,
                              void* d_out, int out_size, void* d_ws, size_t ws_size,
                              hipStream_t stream)
{
    (void)in_sizes; (void)n_in; (void)out_size; (void)ws_size;
    const float* img     = (const float*)d_in[0];
    const float* patch_w = (const float*)d_in[1];
    const float* patch_b = (const float*)d_in[2];
    const float* pos_emb = (const float*)d_in[3];
    const float* ln1_s   = (const float*)d_in[4];
    const float* ln1_b   = (const float*)d_in[5];
    const float* ln2_s   = (const float*)d_in[6];
    const float* ln2_b   = (const float*)d_in[7];
    const float* qkv_w[3] = {(const float*)d_in[8],  (const float*)d_in[12], (const float*)d_in[16]};
    const float* out_w[3] = {(const float*)d_in[9],  (const float*)d_in[13], (const float*)d_in[17]};
    const float* out_b[3] = {(const float*)d_in[10], (const float*)d_in[14], (const float*)d_in[18]};
    const float* biasT[3] = {(const float*)d_in[11], (const float*)d_in[15], (const float*)d_in[19]};
    const float* ff_w1 = (const float*)d_in[20];
    const float* ff_b1 = (const float*)d_in[21];
    const float* ff_w2 = (const float*)d_in[22];
    const float* ff_b2 = (const float*)d_in[23];
    float* out = (float*)d_out;

    const int HS[3] = {2,4,8};
    char* ws = (char*)d_ws;
    size_t off = 0;
    auto alloc = [&](size_t bytes) -> void* {
        void* p = ws + off; off += (bytes + 255) & ~(size_t)255; return p;
    };
    u16*   pwT  = (u16*)  alloc(512ull*32768*2);
    float* part = (float*)alloc(8ull*4096*512*4);
    float* x    = (float*)alloc(4096ull*512*4);
    u16*   xn   = (u16*)  alloc(4096ull*512*2);
    u16*   qkv  = (u16*)  alloc(4096ull*1536*2);
    u16*   ob   = (u16*)  alloc(4096ull*512*2);
    u16*   mid  = (u16*)  alloc(4096ull*256*2);
    u16* qkvT[3]; u16* outT[3]; u16* f1T[3]; u16* f2T[3];
    for (int l = 0; l < 3; ++l) {
        int inner = 64*HS[l];
        qkvT[l] = (u16*)alloc((size_t)3*inner*512*2);
        outT[l] = (u16*)alloc((size_t)512*inner*2);
        f1T[l]  = (u16*)alloc((size_t)256*512*2);
        f2T[l]  = (u16*)alloc((size_t)512*256*2);
    }

    // ---- weight prep (once, up front) ----
    k_prep_pw<<<dim3(1024,16), 256, 0, stream>>>(patch_w, pwT);
    PrepArgs pa;
    for (int l = 0; l < 3; ++l) {
        int inner = 64*HS[l];
        pa.src[l]   = qkv_w[l];              pa.K[l]   = 512;   pa.N[l]   = 3*inner; pa.dst[l]   = qkvT[l];
        pa.src[3+l] = out_w[l];              pa.K[3+l] = inner; pa.N[3+l] = 512;     pa.dst[3+l] = outT[l];
        pa.src[6+l] = ff_w1 + (size_t)l*512*256; pa.K[6+l] = 512; pa.N[6+l] = 256;   pa.dst[6+l] = f1T[l];
        pa.src[9+l] = ff_w2 + (size_t)l*256*512; pa.K[9+l] = 256; pa.N[9+l] = 512;   pa.dst[9+l] = f2T[l];
    }
    k_prep_weights<<<dim3(16,48,12), 256, 0, stream>>>(pa);

    // ---- patch embed: part[z] = A_z @ B_z^T ; x = pb + pe + sum_z part[z] ----
    k_gemm_patch<<<1024, 256, 0, stream>>>(img, pwT, part);
    k_reduce_x<<<2048, 256, 0, stream>>>(part, patch_b, pos_emb, x);

    // ---- transformer layers ----
    for (int l = 0; l < 3; ++l) {
        int h = HS[l], inner = 64*h, n3 = 3*inner;
        k_ln<<<1024, 256, 0, stream>>>(x, ln1_s + l*512, ln1_b + l*512, xn);
        k_gemm64<1><<<dim3(64, n3/64), 256, 0, stream>>>(xn, 512, qkvT[l], 512, 512,
                                                         nullptr, qkv, n3, nullptr);
        k_attn<<<dim3(16, h, 4), 256, 0, stream>>>(qkv, biasT[l], ob, h);
        k_gemm64<3><<<dim3(64, 8), 256, 0, stream>>>(ob, inner, outT[l], inner, inner,
                                                     x, nullptr, 512, out_b[l]);
        k_ln<<<1024, 256, 0, stream>>>(x, ln2_s + l*512, ln2_b + l*512, xn);
        k_gemm64<2><<<dim3(64, 4), 256, 0, stream>>>(xn, 512, f1T[l], 512, 512,
                                                     nullptr, mid, 256, ff_b1 + l*256);
        k_gemm64<3><<<dim3(64, 8), 256, 0, stream>>>(mid, 256, f2T[l], 256, 256,
                                                     x, nullptr, 512, ff_b2 + l*512);
    }
    k_out_transpose<<<dim3(16, 32, 4), 256, 0, stream>>>(x, out);
}